// Round 2
// baseline (2850.153 us; speedup 1.0000x reference)
//
#include <hip/hip_runtime.h>
#include <cstdint>
#include <cstddef>

// ---------------------------------------------------------------------------
// Model dims (fixed): B=64 S=256 E=1024 H=16 D=64 NL=2 FF=4096; T=16384 rows.
// h (residual stream, f32) lives in d_out. Workspace budget ~120 MiB.
// ---------------------------------------------------------------------------

typedef __attribute__((ext_vector_type(4))) float f32x4;
typedef __attribute__((ext_vector_type(8))) __bf16 bf16x8;
typedef __attribute__((ext_vector_type(4))) unsigned int u32x4;
typedef __attribute__((ext_vector_type(8))) unsigned short u16x8;
typedef __attribute__((ext_vector_type(4))) unsigned short u16x4;

__device__ __forceinline__ unsigned short f2bf(float x) {
  unsigned int u = __builtin_bit_cast(unsigned int, x);
  u += 0x7fffu + ((u >> 16) & 1u);          // RNE
  return (unsigned short)(u >> 16);
}
__device__ __forceinline__ float bflo(unsigned int u) {
  return __builtin_bit_cast(float, u << 16);
}
__device__ __forceinline__ float bfhi(unsigned int u) {
  return __builtin_bit_cast(float, u & 0xffff0000u);
}
__device__ __forceinline__ float gelu_new(float x) {
  float x3 = x * x * x;
  float u = 0.7978845608028654f * (x + 0.044715f * x3);
  return 0.5f * x * (1.0f + tanhf(u));
}

// ---------------------------------------------------------------------------
// Weight convert+transpose: W f32 [K,N] -> Wt bf16 [N,K]
// ---------------------------------------------------------------------------
__global__ __launch_bounds__(256) void transpose_bf16(
    const float* __restrict__ W, unsigned short* __restrict__ Wt, int K, int N) {
  __shared__ float tile[32][33];
  const int n0 = blockIdx.x * 32, k0 = blockIdx.y * 32;
  const int tx = threadIdx.x, ty = threadIdx.y;
#pragma unroll
  for (int j = 0; j < 32; j += 8)
    tile[ty + j][tx] = W[(size_t)(k0 + ty + j) * N + n0 + tx];
  __syncthreads();
#pragma unroll
  for (int j = 0; j < 32; j += 8)
    Wt[(size_t)(n0 + ty + j) * K + k0 + tx] = f2bf(tile[tx][ty + j]);
}

// ---------------------------------------------------------------------------
// h = sentence + wpe[s]   (f32, one float4 per thread; h == d_out)
// ---------------------------------------------------------------------------
__global__ __launch_bounds__(256) void add_wpe_kernel(
    const float* __restrict__ sent, const float* __restrict__ wpe,
    float* __restrict__ h) {
  const size_t i = (size_t)blockIdx.x * 256 + threadIdx.x;  // float4 index
  const size_t e4 = i & 255;
  const size_t row = i >> 8;
  const size_t s = row & 255;
  f32x4 a = ((const f32x4*)sent)[i];
  f32x4 w = ((const f32x4*)wpe)[s * 256 + e4];
  ((f32x4*)h)[i] = a + w;
}

// ---------------------------------------------------------------------------
// LayerNorm over E=1024: one block per row. OUTF32=0 -> bf16; 1 -> f32
// (final LN runs in-place on d_out: each thread reads only what it writes).
// ---------------------------------------------------------------------------
template <int OUTF32>
__global__ __launch_bounds__(256) void ln_kernel(
    const float* __restrict__ hin, const float* __restrict__ g,
    const float* __restrict__ bb, void* __restrict__ outp) {
  const int row = blockIdx.x, t = threadIdx.x;
  const f32x4 v = ((const f32x4*)(hin + (size_t)row * 1024))[t];
  float s = v.x + v.y + v.z + v.w;
  float sq = v.x * v.x + v.y * v.y + v.z * v.z + v.w * v.w;
#pragma unroll
  for (int off = 32; off; off >>= 1) {
    s += __shfl_xor(s, off, 64);
    sq += __shfl_xor(sq, off, 64);
  }
  __shared__ float red[8];
  if ((t & 63) == 0) { red[t >> 6] = s; red[4 + (t >> 6)] = sq; }
  __syncthreads();
  s = red[0] + red[1] + red[2] + red[3];
  sq = red[4] + red[5] + red[6] + red[7];
  const float mean = s * (1.0f / 1024.0f);
  const float var = sq * (1.0f / 1024.0f) - mean * mean;
  const float rs = rsqrtf(var + 1e-5f);
  const f32x4 gv = ((const f32x4*)g)[t];
  const f32x4 bv = ((const f32x4*)bb)[t];
  float y0 = (v.x - mean) * rs * gv.x + bv.x;
  float y1 = (v.y - mean) * rs * gv.y + bv.y;
  float y2 = (v.z - mean) * rs * gv.z + bv.z;
  float y3 = (v.w - mean) * rs * gv.w + bv.w;
  if (OUTF32) {
    f32x4 o; o.x = y0; o.y = y1; o.z = y2; o.w = y3;
    ((f32x4*)outp)[(size_t)row * 256 + t] = o;
  } else {
    u16x4 pk;
    pk.x = f2bf(y0); pk.y = f2bf(y1); pk.z = f2bf(y2); pk.w = f2bf(y3);
    ((u16x4*)outp)[(size_t)row * 256 + t] = pk;
  }
}

// ---------------------------------------------------------------------------
// GEMM: C[M,N] = A[M,K](bf16) * Bt[N,K](bf16)^T  (+bias)
// m97 structure: 128x128 tile, BK=32, 4 waves (2x2), global_load_lds w=16.
// EPI: 0 = bf16 (+bias), 1 = bf16 gelu(+bias), 2 = f32 residual +=
// ---------------------------------------------------------------------------
template <int EPI>
__global__ __launch_bounds__(256) void gemm_bt(
    const unsigned short* __restrict__ A, const unsigned short* __restrict__ Bt,
    const float* __restrict__ bias, unsigned short* __restrict__ Cb,
    float* __restrict__ Hres, int N, int K) {
  __shared__ alignas(16) unsigned short As[128 * 32];
  __shared__ alignas(16) unsigned short Bs[128 * 32];
  const int t = threadIdx.x;
  const int w = t >> 6, l = t & 63;
  const int wr = w >> 1, wc = w & 1;
  const int row0 = blockIdx.y * 128, col0 = blockIdx.x * 128;

  f32x4 acc[4][4];
#pragma unroll
  for (int m = 0; m < 4; ++m)
#pragma unroll
    for (int n = 0; n < 4; ++n) {
      acc[m][n].x = 0.f; acc[m][n].y = 0.f; acc[m][n].z = 0.f; acc[m][n].w = 0.f;
    }

  const int lrow = l >> 2;          // 0..15 : row within 16-row chunk
  const int lcol = (l & 3) * 8;     // 0,8,16,24 : k column start
  const int fr = l & 15, fk = (l >> 4) * 8;

  for (int k0 = 0; k0 < K; k0 += 32) {
    __syncthreads();
#pragma unroll
    for (int i = 0; i < 2; ++i) {
      const int chunk = i * 4 + w;              // 0..7, 16 rows each
      const int r = chunk * 16 + lrow;
      __builtin_amdgcn_global_load_lds(
          (const __attribute__((address_space(1))) void*)(A + (size_t)(row0 + r) * K + k0 + lcol),
          (__attribute__((address_space(3))) void*)(As + chunk * 512), 16, 0, 0);
      __builtin_amdgcn_global_load_lds(
          (const __attribute__((address_space(1))) void*)(Bt + (size_t)(col0 + r) * K + k0 + lcol),
          (__attribute__((address_space(3))) void*)(Bs + chunk * 512), 16, 0, 0);
    }
    __syncthreads();

    bf16x8 af[4], bfr[4];
#pragma unroll
    for (int m = 0; m < 4; ++m)
      af[m] = *(const bf16x8*)(As + (wr * 64 + m * 16 + fr) * 32 + fk);
#pragma unroll
    for (int n = 0; n < 4; ++n)
      bfr[n] = *(const bf16x8*)(Bs + (wc * 64 + n * 16 + fr) * 32 + fk);
#pragma unroll
    for (int m = 0; m < 4; ++m)
#pragma unroll
      for (int n = 0; n < 4; ++n)
        acc[m][n] = __builtin_amdgcn_mfma_f32_16x16x32_bf16(af[m], bfr[n], acc[m][n], 0, 0, 0);
  }

  const int cr = (l >> 4) * 4, cc = l & 15;
#pragma unroll
  for (int m = 0; m < 4; ++m) {
#pragma unroll
    for (int n = 0; n < 4; ++n) {
      const int col = col0 + wc * 64 + n * 16 + cc;
      const float bi = bias[col];
#pragma unroll
      for (int r = 0; r < 4; ++r) {
        const int row = row0 + wr * 64 + m * 16 + cr + r;
        float v = acc[m][n][r] + bi;
        if (EPI == 0) {
          Cb[(size_t)row * N + col] = f2bf(v);
        } else if (EPI == 1) {
          Cb[(size_t)row * N + col] = f2bf(gelu_new(v));
        } else {
          Hres[(size_t)row * N + col] += v;
        }
      }
    }
  }
}

// ---------------------------------------------------------------------------
// Attention: one block per (local batch, head); qkv buffer covers 32 batches.
// Thread t owns query row t; K,V in LDS; two-pass online softmax; causal.
// ---------------------------------------------------------------------------
__device__ __forceinline__ float dot64(const float* qf, const unsigned short* krow) {
  const u32x4* kr = (const u32x4*)krow;
  float s = 0.f;
#pragma unroll
  for (int j = 0; j < 8; ++j) {
    u32x4 kv = kr[j];
    s += bflo(kv.x) * qf[j * 8 + 0] + bfhi(kv.x) * qf[j * 8 + 1];
    s += bflo(kv.y) * qf[j * 8 + 2] + bfhi(kv.y) * qf[j * 8 + 3];
    s += bflo(kv.z) * qf[j * 8 + 4] + bfhi(kv.z) * qf[j * 8 + 5];
    s += bflo(kv.w) * qf[j * 8 + 6] + bfhi(kv.w) * qf[j * 8 + 7];
  }
  return s;
}

__global__ __launch_bounds__(256) void attn_kernel(
    const unsigned short* __restrict__ qkv, unsigned short* __restrict__ aout,
    int b0) {
  __shared__ alignas(16) unsigned short Ks[256 * 64];  // 32 KiB
  __shared__ alignas(16) unsigned short Vs[256 * 64];  // 32 KiB
  const int bh = blockIdx.x;          // 0..511
  const int bl = bh >> 4, hd = bh & 15;
  const size_t base = (size_t)bl * 256 * 3072 + (size_t)hd * 64;
  const int t = threadIdx.x;

#pragma unroll
  for (int i = 0; i < 4; ++i) {
    const int s = i * 64 + (t >> 2);
    const int c = (t & 3) * 16;
    const unsigned short* gk = qkv + base + (size_t)s * 3072 + 1024 + c;
    const unsigned short* gv = gk + 1024;
    *(u16x8*)(Ks + s * 64 + c) = *(const u16x8*)gk;
    *(u16x8*)(Ks + s * 64 + c + 8) = *(const u16x8*)(gk + 8);
    *(u16x8*)(Vs + s * 64 + c) = *(const u16x8*)gv;
    *(u16x8*)(Vs + s * 64 + c + 8) = *(const u16x8*)(gv + 8);
  }

  float qf[64];
  {
    const u32x4* gq = (const u32x4*)(qkv + base + (size_t)t * 3072);
#pragma unroll
    for (int j = 0; j < 8; ++j) {
      u32x4 v = gq[j];
      qf[j * 8 + 0] = bflo(v.x); qf[j * 8 + 1] = bfhi(v.x);
      qf[j * 8 + 2] = bflo(v.y); qf[j * 8 + 3] = bfhi(v.y);
      qf[j * 8 + 4] = bflo(v.z); qf[j * 8 + 5] = bfhi(v.z);
      qf[j * 8 + 6] = bflo(v.w); qf[j * 8 + 7] = bfhi(v.w);
    }
  }
  __syncthreads();

  const float scale = 0.125f;  // 1/sqrt(64)
  float m = -3.0e38f, lsum = 0.f;
  for (int k = 0; k <= t; ++k) {
    float s = dot64(qf, Ks + k * 64) * scale;
    float mn = fmaxf(m, s);
    lsum = lsum * __expf(m - mn) + __expf(s - mn);
    m = mn;
  }

  float o[64];
#pragma unroll
  for (int d = 0; d < 64; ++d) o[d] = 0.f;
  for (int k = 0; k <= t; ++k) {
    float s = dot64(qf, Ks + k * 64) * scale;
    float p = __expf(s - m);
    const u32x4* vr = (const u32x4*)(Vs + k * 64);
#pragma unroll
    for (int j = 0; j < 8; ++j) {
      u32x4 vv = vr[j];
      o[j * 8 + 0] += p * bflo(vv.x); o[j * 8 + 1] += p * bfhi(vv.x);
      o[j * 8 + 2] += p * bflo(vv.y); o[j * 8 + 3] += p * bfhi(vv.y);
      o[j * 8 + 4] += p * bflo(vv.z); o[j * 8 + 5] += p * bfhi(vv.z);
      o[j * 8 + 6] += p * bflo(vv.w); o[j * 8 + 7] += p * bfhi(vv.w);
    }
  }
  const float inv = 1.0f / lsum;
  unsigned short* go = aout + (size_t)((b0 + bl) * 256 + t) * 1024 + hd * 64;
#pragma unroll
  for (int j = 0; j < 8; ++j) {
    u16x8 pk;
#pragma unroll
    for (int e = 0; e < 8; ++e) pk[e] = f2bf(o[j * 8 + e] * inv);
    *(u16x8*)(go + j * 8) = pk;
  }
}

// ---------------------------------------------------------------------------
// Loss: mean((h[0,:-1,:]-sent[0,1:,:])^2)
// ---------------------------------------------------------------------------
__device__ __forceinline__ float block_reduce_sum256(float v) {
#pragma unroll
  for (int off = 32; off; off >>= 1) v += __shfl_xor(v, off, 64);
  __shared__ float red[4];
  const int t = threadIdx.x;
  if ((t & 63) == 0) red[t >> 6] = v;
  __syncthreads();
  return red[0] + red[1] + red[2] + red[3];
}

__global__ __launch_bounds__(256) void loss_partial(
    const float* __restrict__ hf, const float* __restrict__ sent,
    float* __restrict__ part) {
  const int s = blockIdx.x, t = threadIdx.x;  // s in 0..254
  f32x4 a = ((const f32x4*)(hf + (size_t)s * 1024))[t];
  f32x4 b = ((const f32x4*)(sent + (size_t)(s + 1) * 1024))[t];
  f32x4 d = a - b;
  float v = d.x * d.x + d.y * d.y + d.z * d.z + d.w * d.w;
  float tot = block_reduce_sum256(v);
  if (t == 0) part[s] = tot;
}

__global__ __launch_bounds__(256) void loss_final(
    const float* __restrict__ part, float* __restrict__ out) {
  const int t = threadIdx.x;
  float v = (t < 255) ? part[t] : 0.f;
  float s = block_reduce_sum256(v);
  if (t == 0) out[0] = s * (1.0f / (255.0f * 1024.0f));
}

// ---------------------------------------------------------------------------
// Workspace layout (bytes) — total ~120 MiB
// ---------------------------------------------------------------------------
constexpr size_t OFF_X     = 0;                      // bf16 x/a union [16384,1024]  32 MiB
constexpr size_t OFF_QKV   = 33554432;               // union: qkv-chunk 48MiB / m-chunk 64MiB
constexpr size_t OFF_WQKV  = OFF_QKV + 67108864;     // bf16 Wt qkv  [3072,1024]  6 MiB
constexpr size_t OFF_WPROJ = OFF_WQKV + 6291456;     // bf16 Wt proj [1024,1024]  2 MiB
constexpr size_t OFF_WFC   = OFF_WPROJ + 2097152;    // bf16 Wt fc   [4096,1024]  8 MiB
constexpr size_t OFF_WMLP  = OFF_WFC + 8388608;      // bf16 Wt mlp  [1024,4096]  8 MiB
constexpr size_t OFF_PART  = OFF_WMLP + 8388608;     // f32 partials (1 KiB)

extern "C" void kernel_launch(void* const* d_in, const int* in_sizes, int n_in,
                              void* d_out, int out_size, void* d_ws, size_t ws_size,
                              hipStream_t stream) {
  (void)in_sizes; (void)n_in; (void)out_size; (void)ws_size;
  const float* sent    = (const float*)d_in[0];
  const float* wpe     = (const float*)d_in[1];
  const float* ln1_g   = (const float*)d_in[2];
  const float* ln1_b   = (const float*)d_in[3];
  const float* attn_w  = (const float*)d_in[4];
  const float* attn_b  = (const float*)d_in[5];
  const float* attn_pw = (const float*)d_in[6];
  const float* attn_pb = (const float*)d_in[7];
  const float* ln2_g   = (const float*)d_in[8];
  const float* ln2_b   = (const float*)d_in[9];
  const float* fc_w    = (const float*)d_in[10];
  const float* fc_b    = (const float*)d_in[11];
  const float* mlp_w   = (const float*)d_in[12];
  const float* mlp_b   = (const float*)d_in[13];
  const float* lnf_g   = (const float*)d_in[14];
  const float* lnf_b   = (const float*)d_in[15];
  float* out_h = (float*)d_out;

  char* ws = (char*)d_ws;
  float* h              = out_h;  // residual stream lives in d_out
  unsigned short* xb    = (unsigned short*)(ws + OFF_X);    // LN out / attn out
  unsigned short* qkvb  = (unsigned short*)(ws + OFF_QKV);  // qkv chunk
  unsigned short* mb    = (unsigned short*)(ws + OFF_QKV);  // m chunk (union)
  unsigned short* wqkv  = (unsigned short*)(ws + OFF_WQKV);
  unsigned short* wproj = (unsigned short*)(ws + OFF_WPROJ);
  unsigned short* wfc   = (unsigned short*)(ws + OFF_WFC);
  unsigned short* wmlp  = (unsigned short*)(ws + OFF_WMLP);
  float* part           = (float*)(ws + OFF_PART);

  add_wpe_kernel<<<16384, 256, 0, stream>>>(sent, wpe, h);

  const dim3 tb(32, 8, 1);
  for (int i = 0; i < 2; ++i) {
    // per-layer weight transpose (f32 [K,N] -> bf16 [N,K]) into reused buffers
    transpose_bf16<<<dim3(96, 32), tb, 0, stream>>>(
        attn_w + (size_t)i * 1024 * 3072, wqkv, 1024, 3072);
    transpose_bf16<<<dim3(32, 32), tb, 0, stream>>>(
        attn_pw + (size_t)i * 1024 * 1024, wproj, 1024, 1024);
    transpose_bf16<<<dim3(128, 32), tb, 0, stream>>>(
        fc_w + (size_t)i * 1024 * 4096, wfc, 1024, 4096);
    transpose_bf16<<<dim3(32, 128), tb, 0, stream>>>(
        mlp_w + (size_t)i * 4096 * 1024, wmlp, 4096, 1024);

    // --- attention block ---
    ln_kernel<0><<<16384, 256, 0, stream>>>(h, ln1_g + i * 1024, ln1_b + i * 1024, xb);
    for (int c = 0; c < 2; ++c) {   // 8192-row (32-batch) chunks
      const size_t r0 = (size_t)c * 8192;
      gemm_bt<0><<<dim3(24, 64), 256, 0, stream>>>(
          xb + r0 * 1024, wqkv, attn_b + i * 3072, qkvb, nullptr, 3072, 1024);
      attn_kernel<<<512, 256, 0, stream>>>(qkvb, xb, c * 32);  // ab aliases xb
    }
    gemm_bt<2><<<dim3(8, 128), 256, 0, stream>>>(
        xb, wproj, attn_pb + i * 1024, nullptr, h, 1024, 1024);

    // --- MLP block ---
    ln_kernel<0><<<16384, 256, 0, stream>>>(h, ln2_g + i * 1024, ln2_b + i * 1024, xb);
    for (int c = 0; c < 2; ++c) {
      const size_t r0 = (size_t)c * 8192;
      gemm_bt<1><<<dim3(32, 64), 256, 0, stream>>>(
          xb + r0 * 1024, wfc, fc_b + i * 4096, mb, nullptr, 4096, 1024);
      gemm_bt<2><<<dim3(8, 64), 256, 0, stream>>>(
          mb, wmlp, mlp_b + i * 1024, nullptr, h + r0 * 1024, 1024, 4096);
    }
  }

  ln_kernel<1><<<16384, 256, 0, stream>>>(h, lnf_g, lnf_b, out_h);
  loss_partial<<<255, 256, 0, stream>>>(out_h, sent, part);
  loss_final<<<1, 256, 0, stream>>>(part, out_h + 16777216);
}

// Round 3
// 1697.213 us; speedup vs baseline: 1.6793x; 1.6793x over previous
//
#include <hip/hip_runtime.h>
#include <cstdint>
#include <cstddef>

// ---------------------------------------------------------------------------
// Model dims (fixed): B=64 S=256 E=1024 H=16 D=64 NL=2 FF=4096; T=16384 rows.
// h (residual stream, f32) lives in d_out. Workspace budget ~120 MiB.
// ---------------------------------------------------------------------------

typedef __attribute__((ext_vector_type(4))) float f32x4;
typedef __attribute__((ext_vector_type(16))) float f32x16;
typedef __attribute__((ext_vector_type(8))) __bf16 bf16x8;
typedef __attribute__((ext_vector_type(4))) unsigned int u32x4;
typedef __attribute__((ext_vector_type(8))) unsigned short u16x8;
typedef __attribute__((ext_vector_type(4))) unsigned short u16x4;

__device__ __forceinline__ unsigned short f2bf(float x) {
  unsigned int u = __builtin_bit_cast(unsigned int, x);
  u += 0x7fffu + ((u >> 16) & 1u);          // RNE
  return (unsigned short)(u >> 16);
}
__device__ __forceinline__ float gelu_new(float x) {
  float x3 = x * x * x;
  float u = 0.7978845608028654f * (x + 0.044715f * x3);
  return 0.5f * x * (1.0f + tanhf(u));
}
// v_cvt_pk_bf16_f32: D[15:0]=bf16(lo), D[31:16]=bf16(hi)
__device__ __forceinline__ unsigned int cvtpk(float lo, float hi) {
  unsigned int r;
  asm("v_cvt_pk_bf16_f32 %0, %1, %2" : "=v"(r) : "v"(lo), "v"(hi));
  return r;
}
// v_permlane32_swap_b32: a.lanes[32:63] <-> b.lanes[0:31]
__device__ __forceinline__ void plswap(unsigned int& a, unsigned int& b) {
  asm("v_permlane32_swap_b32 %0, %1" : "+v"(a), "+v"(b));
}

// ---------------------------------------------------------------------------
// Weight convert+transpose: W f32 [K,N] -> Wt bf16 [N,K]
// ---------------------------------------------------------------------------
__global__ __launch_bounds__(256) void transpose_bf16(
    const float* __restrict__ W, unsigned short* __restrict__ Wt, int K, int N) {
  __shared__ float tile[32][33];
  const int n0 = blockIdx.x * 32, k0 = blockIdx.y * 32;
  const int tx = threadIdx.x, ty = threadIdx.y;
#pragma unroll
  for (int j = 0; j < 32; j += 8)
    tile[ty + j][tx] = W[(size_t)(k0 + ty + j) * N + n0 + tx];
  __syncthreads();
#pragma unroll
  for (int j = 0; j < 32; j += 8)
    Wt[(size_t)(n0 + ty + j) * K + k0 + tx] = f2bf(tile[tx][ty + j]);
}

// ---------------------------------------------------------------------------
// h = sentence + wpe[s]   (f32, one float4 per thread; h == d_out)
// ---------------------------------------------------------------------------
__global__ __launch_bounds__(256) void add_wpe_kernel(
    const float* __restrict__ sent, const float* __restrict__ wpe,
    float* __restrict__ h) {
  const size_t i = (size_t)blockIdx.x * 256 + threadIdx.x;  // float4 index
  const size_t e4 = i & 255;
  const size_t row = i >> 8;
  const size_t s = row & 255;
  f32x4 a = ((const f32x4*)sent)[i];
  f32x4 w = ((const f32x4*)wpe)[s * 256 + e4];
  ((f32x4*)h)[i] = a + w;
}

// ---------------------------------------------------------------------------
// LayerNorm over E=1024: one block per row. OUTF32=0 -> bf16; 1 -> f32
// ---------------------------------------------------------------------------
template <int OUTF32>
__global__ __launch_bounds__(256) void ln_kernel(
    const float* __restrict__ hin, const float* __restrict__ g,
    const float* __restrict__ bb, void* __restrict__ outp) {
  const int row = blockIdx.x, t = threadIdx.x;
  const f32x4 v = ((const f32x4*)(hin + (size_t)row * 1024))[t];
  float s = v.x + v.y + v.z + v.w;
  float sq = v.x * v.x + v.y * v.y + v.z * v.z + v.w * v.w;
#pragma unroll
  for (int off = 32; off; off >>= 1) {
    s += __shfl_xor(s, off, 64);
    sq += __shfl_xor(sq, off, 64);
  }
  __shared__ float red[8];
  if ((t & 63) == 0) { red[t >> 6] = s; red[4 + (t >> 6)] = sq; }
  __syncthreads();
  s = red[0] + red[1] + red[2] + red[3];
  sq = red[4] + red[5] + red[6] + red[7];
  const float mean = s * (1.0f / 1024.0f);
  const float var = sq * (1.0f / 1024.0f) - mean * mean;
  const float rs = rsqrtf(var + 1e-5f);
  const f32x4 gv = ((const f32x4*)g)[t];
  const f32x4 bv = ((const f32x4*)bb)[t];
  float y0 = (v.x - mean) * rs * gv.x + bv.x;
  float y1 = (v.y - mean) * rs * gv.y + bv.y;
  float y2 = (v.z - mean) * rs * gv.z + bv.z;
  float y3 = (v.w - mean) * rs * gv.w + bv.w;
  if (OUTF32) {
    f32x4 o; o.x = y0; o.y = y1; o.z = y2; o.w = y3;
    ((f32x4*)outp)[(size_t)row * 256 + t] = o;
  } else {
    u16x4 pk;
    pk.x = f2bf(y0); pk.y = f2bf(y1); pk.z = f2bf(y2); pk.w = f2bf(y3);
    ((u16x4*)outp)[(size_t)row * 256 + t] = pk;
  }
}

// ---------------------------------------------------------------------------
// GEMM: C[M,N] = A[M,K](bf16) * Bt[N,K](bf16)^T  (+bias)
// m97 structure: 128x128 tile, BK=32, 4 waves (2x2), global_load_lds w=16.
// EPI: 0 = bf16 (+bias), 1 = bf16 gelu(+bias), 2 = f32 residual +=
// ---------------------------------------------------------------------------
template <int EPI>
__global__ __launch_bounds__(256) void gemm_bt(
    const unsigned short* __restrict__ A, const unsigned short* __restrict__ Bt,
    const float* __restrict__ bias, unsigned short* __restrict__ Cb,
    float* __restrict__ Hres, int N, int K) {
  __shared__ alignas(16) unsigned short As[128 * 32];
  __shared__ alignas(16) unsigned short Bs[128 * 32];
  const int t = threadIdx.x;
  const int w = t >> 6, l = t & 63;
  const int wr = w >> 1, wc = w & 1;
  const int row0 = blockIdx.y * 128, col0 = blockIdx.x * 128;

  f32x4 acc[4][4];
#pragma unroll
  for (int m = 0; m < 4; ++m)
#pragma unroll
    for (int n = 0; n < 4; ++n) {
      acc[m][n].x = 0.f; acc[m][n].y = 0.f; acc[m][n].z = 0.f; acc[m][n].w = 0.f;
    }

  const int lrow = l >> 2;
  const int lcol = (l & 3) * 8;
  const int fr = l & 15, fk = (l >> 4) * 8;

  for (int k0 = 0; k0 < K; k0 += 32) {
    __syncthreads();
#pragma unroll
    for (int i = 0; i < 2; ++i) {
      const int chunk = i * 4 + w;
      const int r = chunk * 16 + lrow;
      __builtin_amdgcn_global_load_lds(
          (const __attribute__((address_space(1))) void*)(A + (size_t)(row0 + r) * K + k0 + lcol),
          (__attribute__((address_space(3))) void*)(As + chunk * 512), 16, 0, 0);
      __builtin_amdgcn_global_load_lds(
          (const __attribute__((address_space(1))) void*)(Bt + (size_t)(col0 + r) * K + k0 + lcol),
          (__attribute__((address_space(3))) void*)(Bs + chunk * 512), 16, 0, 0);
    }
    __syncthreads();

    bf16x8 af[4], bfr[4];
#pragma unroll
    for (int m = 0; m < 4; ++m)
      af[m] = *(const bf16x8*)(As + (wr * 64 + m * 16 + fr) * 32 + fk);
#pragma unroll
    for (int n = 0; n < 4; ++n)
      bfr[n] = *(const bf16x8*)(Bs + (wc * 64 + n * 16 + fr) * 32 + fk);
#pragma unroll
    for (int m = 0; m < 4; ++m)
#pragma unroll
      for (int n = 0; n < 4; ++n)
        acc[m][n] = __builtin_amdgcn_mfma_f32_16x16x32_bf16(af[m], bfr[n], acc[m][n], 0, 0, 0);
  }

  const int cr = (l >> 4) * 4, cc = l & 15;
#pragma unroll
  for (int m = 0; m < 4; ++m) {
#pragma unroll
    for (int n = 0; n < 4; ++n) {
      const int col = col0 + wc * 64 + n * 16 + cc;
      const float bi = bias[col];
#pragma unroll
      for (int r = 0; r < 4; ++r) {
        const int row = row0 + wr * 64 + m * 16 + cr + r;
        float v = acc[m][n][r] + bi;
        if (EPI == 0) {
          Cb[(size_t)row * N + col] = f2bf(v);
        } else if (EPI == 1) {
          Cb[(size_t)row * N + col] = f2bf(gelu_new(v));
        } else {
          Hres[(size_t)row * N + col] += v;
        }
      }
    }
  }
}

// ---------------------------------------------------------------------------
// MFMA flash attention. One block per (local batch, head); 4 waves; wave w
// owns q rows [64w, 64w+64). mfma_f32_32x32x16_bf16, swapped QK^T:
//   S^T = mfma(A=K_tile, B=Q): lane holds q-col = l&31, k rows over regs.
// Online softmax in exp2 domain. P^T -> PV B-frags via cvt_pk + permlane32
// (T12). PV: O^T = mfma(A=Vt, B=P^T). K LDS chunk-swizzled; V transposed in
// LDS (Vt[64][256], 16B-chunk XOR swizzle). LDS = 64 KiB exactly.
// ---------------------------------------------------------------------------
__global__ __launch_bounds__(256) void attn_mfma(
    const unsigned short* __restrict__ qkv, unsigned short* __restrict__ aout,
    int b0) {
  __shared__ alignas(16) unsigned short Klds[256 * 64];  // 32 KiB, swizzled
  __shared__ alignas(16) unsigned short Vt[64 * 256];    // 32 KiB, transposed+swz
  const int bh = blockIdx.x;
  const int bl = bh >> 4, hd = bh & 15;
  const size_t base = (size_t)bl * 256 * 3072 + (size_t)hd * 64;
  const int t = threadIdx.x;
  const int w = t >> 6, l = t & 63;
  const int lq = l & 31, hl = l >> 5;

  // ---- stage K (chunk-swizzled) and V (transposed, chunk-swizzled) ----
#pragma unroll
  for (int i = 0; i < 8; ++i) {
    const int r = i * 32 + (t >> 3);   // 0..255 (s index)
    const int c = t & 7;               // 16B chunk within 64-elem row
    u16x8 kv = *(const u16x8*)(qkv + base + (size_t)r * 3072 + 1024 + c * 8);
    *(u16x8*)(Klds + r * 64 + ((c ^ (r & 7)) * 8)) = kv;
    u16x8 vv = *(const u16x8*)(qkv + base + (size_t)r * 3072 + 2048 + c * 8);
#pragma unroll
    for (int j = 0; j < 8; ++j) {
      const int d = c * 8 + j;
      Vt[d * 256 + (((r >> 3) ^ (d & 31)) * 8) + (r & 7)] = vv[j];
    }
  }

  // ---- Q fragments (B operand: col q = lq, contraction d = hl*8+j) ----
  const int q0 = w * 64;
  bf16x8 qf[2][4];
#pragma unroll
  for (int n = 0; n < 2; ++n)
#pragma unroll
    for (int d16 = 0; d16 < 4; ++d16)
      qf[n][d16] = *(const bf16x8*)(qkv + base +
          (size_t)(q0 + n * 32 + lq) * 3072 + d16 * 16 + hl * 8);
  __syncthreads();

  const float cs = 0.125f * 1.44269504088896f;  // 1/sqrt(64) * log2(e)
  f32x16 O[2][2];
#pragma unroll
  for (int m = 0; m < 2; ++m)
#pragma unroll
    for (int n = 0; n < 2; ++n)
#pragma unroll
      for (int e = 0; e < 16; ++e) O[m][n][e] = 0.f;
  float mrun[2] = {-3.0e38f, -3.0e38f};
  float lrun[2] = {0.f, 0.f};

  const int ktmax = (q0 + 63) >> 5;
  for (int kt = 0; kt <= ktmax; ++kt) {
    // K A-frags: row k = kt*32+lq, d = d16*16 + hl*8 (+j)
    bf16x8 kf[4];
    const int krow = kt * 32 + lq;
#pragma unroll
    for (int d16 = 0; d16 < 4; ++d16) {
      const int chunk = (d16 * 2 + hl) ^ (krow & 7);
      kf[d16] = *(const bf16x8*)(Klds + krow * 64 + chunk * 8);
    }
    const int nlo = (kt * 32 > q0 + 31) ? 1 : 0;
    bf16x8 pfrag[2][2];
#pragma unroll
    for (int n = 0; n < 2; ++n) {
      if (n < nlo) continue;
      f32x16 s;
#pragma unroll
      for (int e = 0; e < 16; ++e) s[e] = 0.f;
#pragma unroll
      for (int d16 = 0; d16 < 4; ++d16)
        s = __builtin_amdgcn_mfma_f32_32x32x16_bf16(kf[d16], qf[n][d16], s, 0, 0, 0);
      const int qg = q0 + n * 32 + lq;
      float sv[16];
#pragma unroll
      for (int r = 0; r < 16; ++r) {
        const int kg = kt * 32 + (r & 3) + 8 * (r >> 2) + 4 * hl;
        const float x = s[r] * cs;
        sv[r] = (kg > qg) ? -3.0e38f : x;
      }
      float pmax = sv[0];
#pragma unroll
      for (int r = 1; r < 16; ++r) pmax = fmaxf(pmax, sv[r]);
      pmax = fmaxf(pmax, __shfl_xor(pmax, 32, 64));
      const float nm = fmaxf(mrun[n], pmax);
      const float alpha = exp2f(mrun[n] - nm);
      mrun[n] = nm;
      float psum = 0.f;
#pragma unroll
      for (int r = 0; r < 16; ++r) {
        sv[r] = exp2f(sv[r] - nm);
        psum += sv[r];
      }
      psum += __shfl_xor(psum, 32, 64);
      lrun[n] = lrun[n] * alpha + psum;
#pragma unroll
      for (int m = 0; m < 2; ++m)
#pragma unroll
        for (int e = 0; e < 16; ++e) O[m][n][e] *= alpha;
      // T12 repack: P^T C-frag -> PV B-frags (k16 halves h=0,1)
#pragma unroll
      for (int h = 0; h < 2; ++h) {
        unsigned int a0 = cvtpk(sv[h * 8 + 0], sv[h * 8 + 1]);
        unsigned int a1 = cvtpk(sv[h * 8 + 2], sv[h * 8 + 3]);
        unsigned int c0 = cvtpk(sv[h * 8 + 4], sv[h * 8 + 5]);
        unsigned int c1 = cvtpk(sv[h * 8 + 6], sv[h * 8 + 7]);
        plswap(a0, c0);
        plswap(a1, c1);
        u32x4 fw; fw.x = a0; fw.y = a1; fw.z = c0; fw.w = c1;
        pfrag[n][h] = __builtin_bit_cast(bf16x8, fw);
      }
    }
    // PV: O^T[m][n] += Vt_frag * P^T_frag
#pragma unroll
    for (int m = 0; m < 2; ++m)
#pragma unroll
      for (int h = 0; h < 2; ++h) {
        const int d = m * 32 + lq;
        const int chunk = (kt * 4 + h * 2 + hl) ^ (d & 31);
        bf16x8 vf = *(const bf16x8*)(Vt + d * 256 + chunk * 8);
#pragma unroll
        for (int n = 0; n < 2; ++n)
          if (n >= nlo)
            O[m][n] = __builtin_amdgcn_mfma_f32_32x32x16_bf16(vf, pfrag[n][h], O[m][n], 0, 0, 0);
      }
  }

  // ---- epilogue: divide by l, store bf16. O^T: col q = lq, row d by reg ----
#pragma unroll
  for (int n = 0; n < 2; ++n) {
    const float inv = 1.0f / lrun[n];
    const size_t row = (size_t)(b0 + bl) * 256 + q0 + n * 32 + lq;
#pragma unroll
    for (int m = 0; m < 2; ++m) {
#pragma unroll
      for (int qd = 0; qd < 4; ++qd) {
        u16x4 pk;
#pragma unroll
        for (int e = 0; e < 4; ++e) pk[e] = f2bf(O[m][n][qd * 4 + e] * inv);
        *(u16x4*)(aout + row * 1024 + hd * 64 + m * 32 + qd * 8 + hl * 4) = pk;
      }
    }
  }
}

// ---------------------------------------------------------------------------
// Loss: mean((h[0,:-1,:]-sent[0,1:,:])^2)
// ---------------------------------------------------------------------------
__device__ __forceinline__ float block_reduce_sum256(float v) {
#pragma unroll
  for (int off = 32; off; off >>= 1) v += __shfl_xor(v, off, 64);
  __shared__ float red[4];
  const int t = threadIdx.x;
  if ((t & 63) == 0) red[t >> 6] = v;
  __syncthreads();
  return red[0] + red[1] + red[2] + red[3];
}

__global__ __launch_bounds__(256) void loss_partial(
    const float* __restrict__ hf, const float* __restrict__ sent,
    float* __restrict__ part) {
  const int s = blockIdx.x, t = threadIdx.x;
  f32x4 a = ((const f32x4*)(hf + (size_t)s * 1024))[t];
  f32x4 b = ((const f32x4*)(sent + (size_t)(s + 1) * 1024))[t];
  f32x4 d = a - b;
  float v = d.x * d.x + d.y * d.y + d.z * d.z + d.w * d.w;
  float tot = block_reduce_sum256(v);
  if (t == 0) part[s] = tot;
}

__global__ __launch_bounds__(256) void loss_final(
    const float* __restrict__ part, float* __restrict__ out) {
  const int t = threadIdx.x;
  float v = (t < 255) ? part[t] : 0.f;
  float s = block_reduce_sum256(v);
  if (t == 0) out[0] = s * (1.0f / (255.0f * 1024.0f));
}

// ---------------------------------------------------------------------------
// Workspace layout (bytes) — total ~120 MiB
// ---------------------------------------------------------------------------
constexpr size_t OFF_X     = 0;                      // bf16 x/a union [16384,1024]  32 MiB
constexpr size_t OFF_QKV   = 33554432;               // union: qkv-chunk 48MiB / m-chunk 64MiB
constexpr size_t OFF_WQKV  = OFF_QKV + 67108864;     // bf16 Wt qkv  [3072,1024]  6 MiB
constexpr size_t OFF_WPROJ = OFF_WQKV + 6291456;     // bf16 Wt proj [1024,1024]  2 MiB
constexpr size_t OFF_WFC   = OFF_WPROJ + 2097152;    // bf16 Wt fc   [4096,1024]  8 MiB
constexpr size_t OFF_WMLP  = OFF_WFC + 8388608;      // bf16 Wt mlp  [1024,4096]  8 MiB
constexpr size_t OFF_PART  = OFF_WMLP + 8388608;     // f32 partials (1 KiB)

extern "C" void kernel_launch(void* const* d_in, const int* in_sizes, int n_in,
                              void* d_out, int out_size, void* d_ws, size_t ws_size,
                              hipStream_t stream) {
  (void)in_sizes; (void)n_in; (void)out_size; (void)ws_size;
  const float* sent    = (const float*)d_in[0];
  const float* wpe     = (const float*)d_in[1];
  const float* ln1_g   = (const float*)d_in[2];
  const float* ln1_b   = (const float*)d_in[3];
  const float* attn_w  = (const float*)d_in[4];
  const float* attn_b  = (const float*)d_in[5];
  const float* attn_pw = (const float*)d_in[6];
  const float* attn_pb = (const float*)d_in[7];
  const float* ln2_g   = (const float*)d_in[8];
  const float* ln2_b   = (const float*)d_in[9];
  const float* fc_w    = (const float*)d_in[10];
  const float* fc_b    = (const float*)d_in[11];
  const float* mlp_w   = (const float*)d_in[12];
  const float* mlp_b   = (const float*)d_in[13];
  const float* lnf_g   = (const float*)d_in[14];
  const float* lnf_b   = (const float*)d_in[15];
  float* out_h = (float*)d_out;

  char* ws = (char*)d_ws;
  float* h              = out_h;  // residual stream lives in d_out
  unsigned short* xb    = (unsigned short*)(ws + OFF_X);
  unsigned short* qkvb  = (unsigned short*)(ws + OFF_QKV);
  unsigned short* mb    = (unsigned short*)(ws + OFF_QKV);
  unsigned short* wqkv  = (unsigned short*)(ws + OFF_WQKV);
  unsigned short* wproj = (unsigned short*)(ws + OFF_WPROJ);
  unsigned short* wfc   = (unsigned short*)(ws + OFF_WFC);
  unsigned short* wmlp  = (unsigned short*)(ws + OFF_WMLP);
  float* part           = (float*)(ws + OFF_PART);

  add_wpe_kernel<<<16384, 256, 0, stream>>>(sent, wpe, h);

  const dim3 tb(32, 8, 1);
  for (int i = 0; i < 2; ++i) {
    transpose_bf16<<<dim3(96, 32), tb, 0, stream>>>(
        attn_w + (size_t)i * 1024 * 3072, wqkv, 1024, 3072);
    transpose_bf16<<<dim3(32, 32), tb, 0, stream>>>(
        attn_pw + (size_t)i * 1024 * 1024, wproj, 1024, 1024);
    transpose_bf16<<<dim3(128, 32), tb, 0, stream>>>(
        fc_w + (size_t)i * 1024 * 4096, wfc, 1024, 4096);
    transpose_bf16<<<dim3(32, 128), tb, 0, stream>>>(
        mlp_w + (size_t)i * 4096 * 1024, wmlp, 4096, 1024);

    // --- attention block ---
    ln_kernel<0><<<16384, 256, 0, stream>>>(h, ln1_g + i * 1024, ln1_b + i * 1024, xb);
    for (int c = 0; c < 2; ++c) {   // 8192-row (32-batch) chunks
      const size_t r0 = (size_t)c * 8192;
      gemm_bt<0><<<dim3(24, 64), 256, 0, stream>>>(
          xb + r0 * 1024, wqkv, attn_b + i * 3072, qkvb, nullptr, 3072, 1024);
      attn_mfma<<<512, 256, 0, stream>>>(qkvb, xb, c * 32);  // ab aliases xb
    }
    gemm_bt<2><<<dim3(8, 128), 256, 0, stream>>>(
        xb, wproj, attn_pb + i * 1024, nullptr, h, 1024, 1024);

    // --- MLP block ---
    ln_kernel<0><<<16384, 256, 0, stream>>>(h, ln2_g + i * 1024, ln2_b + i * 1024, xb);
    for (int c = 0; c < 2; ++c) {
      const size_t r0 = (size_t)c * 8192;
      gemm_bt<1><<<dim3(32, 64), 256, 0, stream>>>(
          xb + r0 * 1024, wfc, fc_b + i * 4096, mb, nullptr, 4096, 1024);
      gemm_bt<2><<<dim3(8, 64), 256, 0, stream>>>(
          mb, wmlp, mlp_b + i * 1024, nullptr, h + r0 * 1024, 1024, 4096);
    }
  }

  ln_kernel<1><<<16384, 256, 0, stream>>>(h, lnf_g, lnf_b, out_h);
  loss_partial<<<255, 256, 0, stream>>>(out_h, sent, part);
  loss_final<<<1, 256, 0, stream>>>(part, out_h + 16777216);
}

// Round 4
// 1431.667 us; speedup vs baseline: 1.9908x; 1.1855x over previous
//
#include <hip/hip_runtime.h>
#include <cstdint>
#include <cstddef>

// ---------------------------------------------------------------------------
// Model dims (fixed): B=64 S=256 E=1024 H=16 D=64 NL=2 FF=4096; T=16384 rows.
// h (residual stream, f32) lives in d_out. Workspace budget ~120 MiB.
// ---------------------------------------------------------------------------

typedef __attribute__((ext_vector_type(4))) float f32x4;
typedef __attribute__((ext_vector_type(16))) float f32x16;
typedef __attribute__((ext_vector_type(8))) __bf16 bf16x8;
typedef __attribute__((ext_vector_type(4))) unsigned int u32x4;
typedef __attribute__((ext_vector_type(8))) unsigned short u16x8;
typedef __attribute__((ext_vector_type(4))) unsigned short u16x4;

__device__ __forceinline__ unsigned short f2bf(float x) {
  unsigned int u = __builtin_bit_cast(unsigned int, x);
  u += 0x7fffu + ((u >> 16) & 1u);          // RNE
  return (unsigned short)(u >> 16);
}
__device__ __forceinline__ float gelu_new(float x) {
  float x3 = x * x * x;
  float u = 0.7978845608028654f * (x + 0.044715f * x3);
  return 0.5f * x * (1.0f + tanhf(u));
}
__device__ __forceinline__ unsigned int cvtpk(float lo, float hi) {
  unsigned int r;
  asm("v_cvt_pk_bf16_f32 %0, %1, %2" : "=v"(r) : "v"(lo), "v"(hi));
  return r;
}
__device__ __forceinline__ void plswap(unsigned int& a, unsigned int& b) {
  asm("v_permlane32_swap_b32 %0, %1" : "+v"(a), "+v"(b));
}

// ---------------------------------------------------------------------------
// Weight convert+transpose: W f32 [K,N] -> Wt bf16 [N,K]
// ---------------------------------------------------------------------------
__global__ __launch_bounds__(256) void transpose_bf16(
    const float* __restrict__ W, unsigned short* __restrict__ Wt, int K, int N) {
  __shared__ float tile[32][33];
  const int n0 = blockIdx.x * 32, k0 = blockIdx.y * 32;
  const int tx = threadIdx.x, ty = threadIdx.y;
#pragma unroll
  for (int j = 0; j < 32; j += 8)
    tile[ty + j][tx] = W[(size_t)(k0 + ty + j) * N + n0 + tx];
  __syncthreads();
#pragma unroll
  for (int j = 0; j < 32; j += 8)
    Wt[(size_t)(n0 + ty + j) * K + k0 + tx] = f2bf(tile[tx][ty + j]);
}

// ---------------------------------------------------------------------------
// h = sentence + wpe[s]
// ---------------------------------------------------------------------------
__global__ __launch_bounds__(256) void add_wpe_kernel(
    const float* __restrict__ sent, const float* __restrict__ wpe,
    float* __restrict__ h) {
  const size_t i = (size_t)blockIdx.x * 256 + threadIdx.x;
  const size_t e4 = i & 255;
  const size_t row = i >> 8;
  const size_t s = row & 255;
  f32x4 a = ((const f32x4*)sent)[i];
  f32x4 w = ((const f32x4*)wpe)[s * 256 + e4];
  ((f32x4*)h)[i] = a + w;
}

// ---------------------------------------------------------------------------
// LayerNorm over E=1024: one block per row. OUTF32=0 -> bf16; 1 -> f32
// ---------------------------------------------------------------------------
template <int OUTF32>
__global__ __launch_bounds__(256) void ln_kernel(
    const float* __restrict__ hin, const float* __restrict__ g,
    const float* __restrict__ bb, void* __restrict__ outp) {
  const int row = blockIdx.x, t = threadIdx.x;
  const f32x4 v = ((const f32x4*)(hin + (size_t)row * 1024))[t];
  float s = v.x + v.y + v.z + v.w;
  float sq = v.x * v.x + v.y * v.y + v.z * v.z + v.w * v.w;
#pragma unroll
  for (int off = 32; off; off >>= 1) {
    s += __shfl_xor(s, off, 64);
    sq += __shfl_xor(sq, off, 64);
  }
  __shared__ float red[8];
  if ((t & 63) == 0) { red[t >> 6] = s; red[4 + (t >> 6)] = sq; }
  __syncthreads();
  s = red[0] + red[1] + red[2] + red[3];
  sq = red[4] + red[5] + red[6] + red[7];
  const float mean = s * (1.0f / 1024.0f);
  const float var = sq * (1.0f / 1024.0f) - mean * mean;
  const float rs = rsqrtf(var + 1e-5f);
  const f32x4 gv = ((const f32x4*)g)[t];
  const f32x4 bv = ((const f32x4*)bb)[t];
  float y0 = (v.x - mean) * rs * gv.x + bv.x;
  float y1 = (v.y - mean) * rs * gv.y + bv.y;
  float y2 = (v.z - mean) * rs * gv.z + bv.z;
  float y3 = (v.w - mean) * rs * gv.w + bv.w;
  if (OUTF32) {
    f32x4 o; o.x = y0; o.y = y1; o.z = y2; o.w = y3;
    ((f32x4*)outp)[(size_t)row * 256 + t] = o;
  } else {
    u16x4 pk;
    pk.x = f2bf(y0); pk.y = f2bf(y1); pk.z = f2bf(y2); pk.w = f2bf(y3);
    ((u16x4*)outp)[(size_t)row * 256 + t] = pk;
  }
}

// ---------------------------------------------------------------------------
// Pipelined GEMM: C[M,N] = A[M,K](bf16) * Bt[N,K](bf16)^T (+bias)
// BM x 256 tile (BM = 256 or 128), BK=32, 8 waves (2x4), 512 threads.
// 4-deep LDS pipeline, counted vmcnt (T4), raw s_barrier, XOR chunk swizzle
// (T2), setprio around MFMA (T5), XCD-chunk + 4-wide-stripe block swizzle (T1).
// EPI: 0 = bf16 (+bias), 1 = bf16 gelu(+bias), 2 = f32 residual +=
// Requires: M%BM==0, N%256==0, K%32==0, (gx*gy)%8==0, gx%4==0.
// ---------------------------------------------------------------------------
template <int BM, int EPI>
__global__ __launch_bounds__(512, 2) void gemm8(
    const unsigned short* __restrict__ A, const unsigned short* __restrict__ Bt,
    const float* __restrict__ bias, unsigned short* __restrict__ Cb,
    float* __restrict__ Hres, int N, int K, int gx, int gy) {
  constexpr int M_REP = BM / 32;            // frags per wave in M (8 or 4)
  constexpr int A_LOADS = BM / 128;         // per-thread A loads per tile (2 or 1)
  constexpr int A_HALF = BM * 32;           // A elements per tile
  constexpr int TILE_E = A_HALF + 8192;     // + B elements (256*32)
  __shared__ alignas(16) unsigned short lds[4 * TILE_E];

  // ---- block swizzle: XCD chunk (bijective, nwg%8==0) + 4-wide bx stripes ----
  const int nwg = gx * gy;
  const int d = blockIdx.x;
  const int wrk = (d & 7) * (nwg >> 3) + (d >> 3);
  const int stripe = gy * 4;
  const int cg = wrk / stripe;
  const int rem = wrk - cg * stripe;
  const int by = rem >> 2;
  const int bx = cg * 4 + (rem & 3);
  const int row0 = by * BM, col0 = bx * 256;

  const int t = threadIdx.x;
  const int wid = t >> 6, l = t & 63;
  const int wm = wid >> 2, wn = wid & 3;
  const int fr = l & 15, hl = l >> 4;

  // ---- LDS read offsets (elements), chunk-swizzled ----
  const int swz = (hl ^ (fr & 3)) * 8;
  const int a_rd = (wm * (BM / 2) + fr) * 32 + swz;   // + m*512
  const int b_rd = (wn * 64 + fr) * 32 + swz;         // + n*512

  // ---- staging source pointers (inverse-swizzled per-lane global addr) ----
  const unsigned short* gA[A_LOADS];
#pragma unroll
  for (int j = 0; j < A_LOADS; ++j) {
    const int srow = (wid * A_LOADS + j) * 16 + (l >> 2);
    const int sch = (l & 3) ^ (srow & 3);
    gA[j] = A + (size_t)(row0 + srow) * K + sch * 8;
  }
  const unsigned short* gB[2];
#pragma unroll
  for (int j = 0; j < 2; ++j) {
    const int srow = (wid * 2 + j) * 16 + (l >> 2);
    const int sch = (l & 3) ^ (srow & 3);
    gB[j] = Bt + (size_t)(col0 + srow) * K + sch * 8;
  }

  const int nt = K >> 5;

  auto stageA = [&](int tt, int j) {
    __builtin_amdgcn_global_load_lds(
        (const __attribute__((address_space(1))) void*)(gA[j] + (size_t)tt * 32),
        (__attribute__((address_space(3))) void*)(lds + (tt & 3) * TILE_E + (wid * A_LOADS + j) * 512),
        16, 0, 0);
  };
  auto stageB = [&](int tt, int j) {
    __builtin_amdgcn_global_load_lds(
        (const __attribute__((address_space(1))) void*)(gB[j] + (size_t)tt * 32),
        (__attribute__((address_space(3))) void*)(lds + (tt & 3) * TILE_E + A_HALF + (wid * 2 + j) * 512),
        16, 0, 0);
  };

  // ---- prologue: stage tiles 0..2 ----
#pragma unroll
  for (int tt = 0; tt < 3; ++tt) {
#pragma unroll
    for (int j = 0; j < A_LOADS; ++j) stageA(tt, j);
#pragma unroll
    for (int j = 0; j < 2; ++j) stageB(tt, j);
  }

  f32x4 acc[M_REP][4];
#pragma unroll
  for (int m = 0; m < M_REP; ++m)
#pragma unroll
    for (int n = 0; n < 4; ++n) {
      acc[m][n].x = 0.f; acc[m][n].y = 0.f; acc[m][n].z = 0.f; acc[m][n].w = 0.f;
    }

  for (int tcur = 0; tcur < nt; ++tcur) {
    // boundary: own tile-t loads guaranteed landed (counted, never 0 mid-loop)
    const int rm = nt - 1 - tcur;
    if (rm >= 2) {
      if constexpr (BM == 256) asm volatile("s_waitcnt vmcnt(8)" ::: "memory");
      else                     asm volatile("s_waitcnt vmcnt(6)" ::: "memory");
    } else if (rm == 1) {
      if constexpr (BM == 256) asm volatile("s_waitcnt vmcnt(4)" ::: "memory");
      else                     asm volatile("s_waitcnt vmcnt(3)" ::: "memory");
    } else {
      asm volatile("s_waitcnt vmcnt(0)" ::: "memory");
    }
    __builtin_amdgcn_s_barrier();       // all waves' stages for this tile landed
    asm volatile("" ::: "memory");      // no LDS reads hoisted above barrier

    const unsigned short* Ab = lds + (tcur & 3) * TILE_E;
    const unsigned short* Bb = Ab + A_HALF;
    const bool pf = (tcur + 3) < nt;

    // ---- phase 0: B all n, A m-half 0; MFMA (m-half0 x all n) ----
    bf16x8 bf[4];
#pragma unroll
    for (int n = 0; n < 4; ++n) bf[n] = *(const bf16x8*)(Bb + b_rd + n * 512);
    bf16x8 af[M_REP / 2];
#pragma unroll
    for (int m = 0; m < M_REP / 2; ++m) af[m] = *(const bf16x8*)(Ab + a_rd + m * 512);
    if (pf) { stageA(tcur + 3, 0); stageB(tcur + 3, 0); }
    __builtin_amdgcn_s_setprio(1);
#pragma unroll
    for (int m = 0; m < M_REP / 2; ++m)
#pragma unroll
      for (int n = 0; n < 4; ++n)
        acc[m][n] = __builtin_amdgcn_mfma_f32_16x16x32_bf16(af[m], bf[n], acc[m][n], 0, 0, 0);
    __builtin_amdgcn_s_setprio(0);
    __builtin_amdgcn_s_barrier();
    asm volatile("" ::: "memory");

    // ---- phase 1: A m-half 1; MFMA (m-half1 x all n) ----
    bf16x8 af2[M_REP / 2];
#pragma unroll
    for (int m = 0; m < M_REP / 2; ++m)
      af2[m] = *(const bf16x8*)(Ab + a_rd + (M_REP / 2 + m) * 512);
    if (pf) {
      if constexpr (A_LOADS == 2) stageA(tcur + 3, 1);
      stageB(tcur + 3, 1);
    }
    __builtin_amdgcn_s_setprio(1);
#pragma unroll
    for (int m = 0; m < M_REP / 2; ++m)
#pragma unroll
      for (int n = 0; n < 4; ++n)
        acc[M_REP / 2 + m][n] =
            __builtin_amdgcn_mfma_f32_16x16x32_bf16(af2[m], bf[n], acc[M_REP / 2 + m][n], 0, 0, 0);
    __builtin_amdgcn_s_setprio(0);
  }

  // ---- epilogue ----
  const int cr = hl * 4, cc = fr;
#pragma unroll
  for (int n = 0; n < 4; ++n) {
    const int col = col0 + wn * 64 + n * 16 + cc;
    const float bi = bias[col];
#pragma unroll
    for (int m = 0; m < M_REP; ++m) {
#pragma unroll
      for (int e = 0; e < 4; ++e) {
        const int row = row0 + wm * (BM / 2) + m * 16 + cr + e;
        float v = acc[m][n][e] + bi;
        if (EPI == 0) {
          Cb[(size_t)row * N + col] = f2bf(v);
        } else if (EPI == 1) {
          Cb[(size_t)row * N + col] = f2bf(gelu_new(v));
        } else {
          Hres[(size_t)row * N + col] += v;
        }
      }
    }
  }
}

// ---------------------------------------------------------------------------
// MFMA flash attention (unchanged from round 3; verified).
// ---------------------------------------------------------------------------
__global__ __launch_bounds__(256) void attn_mfma(
    const unsigned short* __restrict__ qkv, unsigned short* __restrict__ aout,
    int b0) {
  __shared__ alignas(16) unsigned short Klds[256 * 64];
  __shared__ alignas(16) unsigned short Vt[64 * 256];
  const int bh = blockIdx.x;
  const int bl = bh >> 4, hd = bh & 15;
  const size_t base = (size_t)bl * 256 * 3072 + (size_t)hd * 64;
  const int t = threadIdx.x;
  const int w = t >> 6, l = t & 63;
  const int lq = l & 31, hl = l >> 5;

#pragma unroll
  for (int i = 0; i < 8; ++i) {
    const int r = i * 32 + (t >> 3);
    const int c = t & 7;
    u16x8 kv = *(const u16x8*)(qkv + base + (size_t)r * 3072 + 1024 + c * 8);
    *(u16x8*)(Klds + r * 64 + ((c ^ (r & 7)) * 8)) = kv;
    u16x8 vv = *(const u16x8*)(qkv + base + (size_t)r * 3072 + 2048 + c * 8);
#pragma unroll
    for (int j = 0; j < 8; ++j) {
      const int d = c * 8 + j;
      Vt[d * 256 + (((r >> 3) ^ (d & 31)) * 8) + (r & 7)] = vv[j];
    }
  }

  const int q0 = w * 64;
  bf16x8 qf[2][4];
#pragma unroll
  for (int n = 0; n < 2; ++n)
#pragma unroll
    for (int d16 = 0; d16 < 4; ++d16)
      qf[n][d16] = *(const bf16x8*)(qkv + base +
          (size_t)(q0 + n * 32 + lq) * 3072 + d16 * 16 + hl * 8);
  __syncthreads();

  const float cs = 0.125f * 1.44269504088896f;
  f32x16 O[2][2];
#pragma unroll
  for (int m = 0; m < 2; ++m)
#pragma unroll
    for (int n = 0; n < 2; ++n)
#pragma unroll
      for (int e = 0; e < 16; ++e) O[m][n][e] = 0.f;
  float mrun[2] = {-3.0e38f, -3.0e38f};
  float lrun[2] = {0.f, 0.f};

  const int ktmax = (q0 + 63) >> 5;
  for (int kt = 0; kt <= ktmax; ++kt) {
    bf16x8 kf[4];
    const int krow = kt * 32 + lq;
#pragma unroll
    for (int d16 = 0; d16 < 4; ++d16) {
      const int chunk = (d16 * 2 + hl) ^ (krow & 7);
      kf[d16] = *(const bf16x8*)(Klds + krow * 64 + chunk * 8);
    }
    const int nlo = (kt * 32 > q0 + 31) ? 1 : 0;
    bf16x8 pfrag[2][2];
#pragma unroll
    for (int n = 0; n < 2; ++n) {
      if (n < nlo) continue;
      f32x16 s;
#pragma unroll
      for (int e = 0; e < 16; ++e) s[e] = 0.f;
#pragma unroll
      for (int d16 = 0; d16 < 4; ++d16)
        s = __builtin_amdgcn_mfma_f32_32x32x16_bf16(kf[d16], qf[n][d16], s, 0, 0, 0);
      const int qg = q0 + n * 32 + lq;
      float sv[16];
#pragma unroll
      for (int r = 0; r < 16; ++r) {
        const int kg = kt * 32 + (r & 3) + 8 * (r >> 2) + 4 * hl;
        const float x = s[r] * cs;
        sv[r] = (kg > qg) ? -3.0e38f : x;
      }
      float pmax = sv[0];
#pragma unroll
      for (int r = 1; r < 16; ++r) pmax = fmaxf(pmax, sv[r]);
      pmax = fmaxf(pmax, __shfl_xor(pmax, 32, 64));
      const float nm = fmaxf(mrun[n], pmax);
      const float alpha = exp2f(mrun[n] - nm);
      mrun[n] = nm;
      float psum = 0.f;
#pragma unroll
      for (int r = 0; r < 16; ++r) {
        sv[r] = exp2f(sv[r] - nm);
        psum += sv[r];
      }
      psum += __shfl_xor(psum, 32, 64);
      lrun[n] = lrun[n] * alpha + psum;
#pragma unroll
      for (int m = 0; m < 2; ++m)
#pragma unroll
        for (int e = 0; e < 16; ++e) O[m][n][e] *= alpha;
#pragma unroll
      for (int h = 0; h < 2; ++h) {
        unsigned int a0 = cvtpk(sv[h * 8 + 0], sv[h * 8 + 1]);
        unsigned int a1 = cvtpk(sv[h * 8 + 2], sv[h * 8 + 3]);
        unsigned int c0 = cvtpk(sv[h * 8 + 4], sv[h * 8 + 5]);
        unsigned int c1 = cvtpk(sv[h * 8 + 6], sv[h * 8 + 7]);
        plswap(a0, c0);
        plswap(a1, c1);
        u32x4 fw; fw.x = a0; fw.y = a1; fw.z = c0; fw.w = c1;
        pfrag[n][h] = __builtin_bit_cast(bf16x8, fw);
      }
    }
#pragma unroll
    for (int m = 0; m < 2; ++m)
#pragma unroll
      for (int h = 0; h < 2; ++h) {
        const int dd = m * 32 + lq;
        const int chunk = (kt * 4 + h * 2 + hl) ^ (dd & 31);
        bf16x8 vf = *(const bf16x8*)(Vt + dd * 256 + chunk * 8);
#pragma unroll
        for (int n = 0; n < 2; ++n)
          if (n >= nlo)
            O[m][n] = __builtin_amdgcn_mfma_f32_32x32x16_bf16(vf, pfrag[n][h], O[m][n], 0, 0, 0);
      }
  }

#pragma unroll
  for (int n = 0; n < 2; ++n) {
    const float inv = 1.0f / lrun[n];
    const size_t row = (size_t)(b0 + bl) * 256 + q0 + n * 32 + lq;
#pragma unroll
    for (int m = 0; m < 2; ++m) {
#pragma unroll
      for (int qd = 0; qd < 4; ++qd) {
        u16x4 pk;
#pragma unroll
        for (int e = 0; e < 4; ++e) pk[e] = f2bf(O[m][n][qd * 4 + e] * inv);
        *(u16x4*)(aout + row * 1024 + hd * 64 + m * 32 + qd * 8 + hl * 4) = pk;
      }
    }
  }
}

// ---------------------------------------------------------------------------
// Loss
// ---------------------------------------------------------------------------
__device__ __forceinline__ float block_reduce_sum256(float v) {
#pragma unroll
  for (int off = 32; off; off >>= 1) v += __shfl_xor(v, off, 64);
  __shared__ float red[4];
  const int t = threadIdx.x;
  if ((t & 63) == 0) red[t >> 6] = v;
  __syncthreads();
  return red[0] + red[1] + red[2] + red[3];
}

__global__ __launch_bounds__(256) void loss_partial(
    const float* __restrict__ hf, const float* __restrict__ sent,
    float* __restrict__ part) {
  const int s = blockIdx.x, t = threadIdx.x;
  f32x4 a = ((const f32x4*)(hf + (size_t)s * 1024))[t];
  f32x4 b = ((const f32x4*)(sent + (size_t)(s + 1) * 1024))[t];
  f32x4 d = a - b;
  float v = d.x * d.x + d.y * d.y + d.z * d.z + d.w * d.w;
  float tot = block_reduce_sum256(v);
  if (t == 0) part[s] = tot;
}

__global__ __launch_bounds__(256) void loss_final(
    const float* __restrict__ part, float* __restrict__ out) {
  const int t = threadIdx.x;
  float v = (t < 255) ? part[t] : 0.f;
  float s = block_reduce_sum256(v);
  if (t == 0) out[0] = s * (1.0f / (255.0f * 1024.0f));
}

// ---------------------------------------------------------------------------
// Workspace layout (bytes) — total ~120 MiB
// ---------------------------------------------------------------------------
constexpr size_t OFF_X     = 0;
constexpr size_t OFF_QKV   = 33554432;
constexpr size_t OFF_WQKV  = OFF_QKV + 67108864;
constexpr size_t OFF_WPROJ = OFF_WQKV + 6291456;
constexpr size_t OFF_WFC   = OFF_WPROJ + 2097152;
constexpr size_t OFF_WMLP  = OFF_WFC + 8388608;
constexpr size_t OFF_PART  = OFF_WMLP + 8388608;

extern "C" void kernel_launch(void* const* d_in, const int* in_sizes, int n_in,
                              void* d_out, int out_size, void* d_ws, size_t ws_size,
                              hipStream_t stream) {
  (void)in_sizes; (void)n_in; (void)out_size; (void)ws_size;
  const float* sent    = (const float*)d_in[0];
  const float* wpe     = (const float*)d_in[1];
  const float* ln1_g   = (const float*)d_in[2];
  const float* ln1_b   = (const float*)d_in[3];
  const float* attn_w  = (const float*)d_in[4];
  const float* attn_b  = (const float*)d_in[5];
  const float* attn_pw = (const float*)d_in[6];
  const float* attn_pb = (const float*)d_in[7];
  const float* ln2_g   = (const float*)d_in[8];
  const float* ln2_b   = (const float*)d_in[9];
  const float* fc_w    = (const float*)d_in[10];
  const float* fc_b    = (const float*)d_in[11];
  const float* mlp_w   = (const float*)d_in[12];
  const float* mlp_b   = (const float*)d_in[13];
  const float* lnf_g   = (const float*)d_in[14];
  const float* lnf_b   = (const float*)d_in[15];
  float* out_h = (float*)d_out;

  char* ws = (char*)d_ws;
  float* h              = out_h;
  unsigned short* xb    = (unsigned short*)(ws + OFF_X);
  unsigned short* qkvb  = (unsigned short*)(ws + OFF_QKV);
  unsigned short* mb    = (unsigned short*)(ws + OFF_QKV);
  unsigned short* wqkv  = (unsigned short*)(ws + OFF_WQKV);
  unsigned short* wproj = (unsigned short*)(ws + OFF_WPROJ);
  unsigned short* wfc   = (unsigned short*)(ws + OFF_WFC);
  unsigned short* wmlp  = (unsigned short*)(ws + OFF_WMLP);
  float* part           = (float*)(ws + OFF_PART);

  add_wpe_kernel<<<16384, 256, 0, stream>>>(sent, wpe, h);

  const dim3 tb(32, 8, 1);
  for (int i = 0; i < 2; ++i) {
    transpose_bf16<<<dim3(96, 32), tb, 0, stream>>>(
        attn_w + (size_t)i * 1024 * 3072, wqkv, 1024, 3072);
    transpose_bf16<<<dim3(32, 32), tb, 0, stream>>>(
        attn_pw + (size_t)i * 1024 * 1024, wproj, 1024, 1024);
    transpose_bf16<<<dim3(128, 32), tb, 0, stream>>>(
        fc_w + (size_t)i * 1024 * 4096, wfc, 1024, 4096);
    transpose_bf16<<<dim3(32, 128), tb, 0, stream>>>(
        mlp_w + (size_t)i * 4096 * 1024, wmlp, 4096, 1024);

    // --- attention block ---
    ln_kernel<0><<<16384, 256, 0, stream>>>(h, ln1_g + i * 1024, ln1_b + i * 1024, xb);
    for (int c = 0; c < 2; ++c) {   // 8192-row (32-batch) chunks
      const size_t r0 = (size_t)c * 8192;
      gemm8<256, 0><<<384, 512, 0, stream>>>(
          xb + r0 * 1024, wqkv, attn_b + i * 3072, qkvb, nullptr, 3072, 1024, 12, 32);
      attn_mfma<<<512, 256, 0, stream>>>(qkvb, xb, c * 32);  // ab aliases xb
    }
    gemm8<256, 2><<<256, 512, 0, stream>>>(
        xb, wproj, attn_pb + i * 1024, nullptr, h, 1024, 1024, 4, 64);

    // --- MLP block ---
    ln_kernel<0><<<16384, 256, 0, stream>>>(h, ln2_g + i * 1024, ln2_b + i * 1024, xb);
    for (int c = 0; c < 2; ++c) {
      const size_t r0 = (size_t)c * 8192;
      gemm8<256, 1><<<512, 512, 0, stream>>>(
          xb + r0 * 1024, wfc, fc_b + i * 4096, mb, nullptr, 4096, 1024, 16, 32);
      gemm8<128, 2><<<256, 512, 0, stream>>>(
          mb, wmlp, mlp_b + i * 1024, nullptr, h + r0 * 1024, 1024, 4096, 4, 64);
    }
  }

  ln_kernel<1><<<16384, 256, 0, stream>>>(h, lnf_g, lnf_b, out_h);
  loss_partial<<<255, 256, 0, stream>>>(out_h, sent, part);
  loss_final<<<1, 256, 0, stream>>>(part, out_h + 16777216);
}

// Round 5
// 1316.931 us; speedup vs baseline: 2.1642x; 1.0871x over previous
//
#include <hip/hip_runtime.h>
#include <cstdint>
#include <cstddef>

// ---------------------------------------------------------------------------
// Model dims (fixed): B=64 S=256 E=1024 H=16 D=64 NL=2 FF=4096; T=16384 rows.
// h (residual stream, f32) lives in d_out. Workspace budget ~120 MiB.
// ---------------------------------------------------------------------------

typedef __attribute__((ext_vector_type(4))) float f32x4;
typedef __attribute__((ext_vector_type(16))) float f32x16;
typedef __attribute__((ext_vector_type(8))) __bf16 bf16x8;
typedef __attribute__((ext_vector_type(4))) unsigned int u32x4;
typedef __attribute__((ext_vector_type(8))) unsigned short u16x8;
typedef __attribute__((ext_vector_type(4))) unsigned short u16x4;

__device__ __forceinline__ unsigned short f2bf(float x) {
  unsigned int u = __builtin_bit_cast(unsigned int, x);
  u += 0x7fffu + ((u >> 16) & 1u);          // RNE
  return (unsigned short)(u >> 16);
}
__device__ __forceinline__ float gelu_new(float x) {
  // 0.5x(1+tanh(u)) == x * sigmoid(2u), u = 0.79788456(x + 0.044715 x^3)
  float u = 0.7978845608028654f * (x + 0.044715f * x * x * x);
  return x * __builtin_amdgcn_rcpf(1.0f + __expf(-2.0f * u));
}
__device__ __forceinline__ unsigned int cvtpk(float lo, float hi) {
  unsigned int r;
  asm("v_cvt_pk_bf16_f32 %0, %1, %2" : "=v"(r) : "v"(lo), "v"(hi));
  return r;
}
__device__ __forceinline__ void plswap(unsigned int& a, unsigned int& b) {
  asm("v_permlane32_swap_b32 %0, %1" : "+v"(a), "+v"(b));
}

// ---------------------------------------------------------------------------
// Weight convert+transpose: W f32 [K,N] -> Wt bf16 [N,K]
// ---------------------------------------------------------------------------
__global__ __launch_bounds__(256) void transpose_bf16(
    const float* __restrict__ W, unsigned short* __restrict__ Wt, int K, int N) {
  __shared__ float tile[32][33];
  const int n0 = blockIdx.x * 32, k0 = blockIdx.y * 32;
  const int tx = threadIdx.x, ty = threadIdx.y;
#pragma unroll
  for (int j = 0; j < 32; j += 8)
    tile[ty + j][tx] = W[(size_t)(k0 + ty + j) * N + n0 + tx];
  __syncthreads();
#pragma unroll
  for (int j = 0; j < 32; j += 8)
    Wt[(size_t)(n0 + ty + j) * K + k0 + tx] = f2bf(tile[tx][ty + j]);
}

// ---------------------------------------------------------------------------
// h = sentence + wpe[s]
// ---------------------------------------------------------------------------
__global__ __launch_bounds__(256) void add_wpe_kernel(
    const float* __restrict__ sent, const float* __restrict__ wpe,
    float* __restrict__ h) {
  const size_t i = (size_t)blockIdx.x * 256 + threadIdx.x;
  const size_t e4 = i & 255;
  const size_t row = i >> 8;
  const size_t s = row & 255;
  f32x4 a = ((const f32x4*)sent)[i];
  f32x4 w = ((const f32x4*)wpe)[s * 256 + e4];
  ((f32x4*)h)[i] = a + w;
}

// ---------------------------------------------------------------------------
// LayerNorm over E=1024: one block per row. OUTF32=0 -> bf16; 1 -> f32
// ---------------------------------------------------------------------------
template <int OUTF32>
__global__ __launch_bounds__(256) void ln_kernel(
    const float* __restrict__ hin, const float* __restrict__ g,
    const float* __restrict__ bb, void* __restrict__ outp) {
  const int row = blockIdx.x, t = threadIdx.x;
  const f32x4 v = ((const f32x4*)(hin + (size_t)row * 1024))[t];
  float s = v.x + v.y + v.z + v.w;
  float sq = v.x * v.x + v.y * v.y + v.z * v.z + v.w * v.w;
#pragma unroll
  for (int off = 32; off; off >>= 1) {
    s += __shfl_xor(s, off, 64);
    sq += __shfl_xor(sq, off, 64);
  }
  __shared__ float red[8];
  if ((t & 63) == 0) { red[t >> 6] = s; red[4 + (t >> 6)] = sq; }
  __syncthreads();
  s = red[0] + red[1] + red[2] + red[3];
  sq = red[4] + red[5] + red[6] + red[7];
  const float mean = s * (1.0f / 1024.0f);
  const float var = sq * (1.0f / 1024.0f) - mean * mean;
  const float rs = rsqrtf(var + 1e-5f);
  const f32x4 gv = ((const f32x4*)g)[t];
  const f32x4 bv = ((const f32x4*)bb)[t];
  float y0 = (v.x - mean) * rs * gv.x + bv.x;
  float y1 = (v.y - mean) * rs * gv.y + bv.y;
  float y2 = (v.z - mean) * rs * gv.z + bv.z;
  float y3 = (v.w - mean) * rs * gv.w + bv.w;
  if (OUTF32) {
    f32x4 o; o.x = y0; o.y = y1; o.z = y2; o.w = y3;
    ((f32x4*)outp)[(size_t)row * 256 + t] = o;
  } else {
    u16x4 pk;
    pk.x = f2bf(y0); pk.y = f2bf(y1); pk.z = f2bf(y2); pk.w = f2bf(y3);
    ((u16x4*)outp)[(size_t)row * 256 + t] = pk;
  }
}

// ---------------------------------------------------------------------------
// 4-phase pipelined GEMM: C[M,N] = A[M,K](bf16) * Bt[N,K](bf16)^T (+bias)
// BM x 256 tile, BK=64, 8 waves (2m x 4n), 512 thr. LDS 2dbuf x (A+B) K-tile,
// chunk^row XOR swizzle (conflict-free ds_read_b128 at quarter-wave), staging
// order {B-lo, B-hi, A-early, A-late} with counted vmcnt(4)/vmcnt(2) (never 0
// mid-loop), raw s_barrier, setprio around MFMA, XCD-chunk block swizzle.
// EPI: 0 = bf16 (+bias), 1 = bf16 gelu(+bias), 2 = f32 residual +=
// Epilogue (EPI 0/1): LDS repack (pitch 144B) -> coalesced u16x8 stores.
// Requires: M%BM==0, N%256==0, K%64==0, nt>=2, (gx*gy)%8==0, gx%4==0.
// ---------------------------------------------------------------------------
template <int BM, int EPI>
__global__ __launch_bounds__(512, 2) void gemm8p(
    const unsigned short* __restrict__ A, const unsigned short* __restrict__ Bt,
    const float* __restrict__ bias, unsigned short* __restrict__ Cb,
    float* __restrict__ Hres, int N, int K, int gx, int gy) {
  constexpr int M_REP = BM / 32;           // 8 or 4
  constexpr int A_E = BM * 64;             // A elems per K-tile
  constexpr int BUF_E = A_E + 16384;       // + B (256x64)
  __shared__ alignas(16) unsigned short smem[2 * BUF_E];

  // ---- block swizzle: XCD chunk (bijective) + 4-wide bx stripes ----
  const int nwg = gx * gy;
  const int dd = blockIdx.x;
  const int wrk = (dd & 7) * (nwg >> 3) + (dd >> 3);
  const int stripe = gy * 4;
  const int cg = wrk / stripe;
  const int rem = wrk - cg * stripe;
  const int by = rem >> 2;
  const int bx = cg * 4 + (rem & 3);
  const int row0 = by * BM, col0 = bx * 256;

  const int t = threadIdx.x;
  const int wid = t >> 6, l = t & 63;
  const int wm = wid >> 2, wn = wid & 3;
  const int fr = l & 15, q4 = l >> 4;

  // frag-read constants: chunk (kk*4+q4) ^ (row&7), row%16 == fr
  const int cx0 = ((q4) ^ (fr & 7)) * 8;
  const int cx1 = ((4 + q4) ^ (fr & 7)) * 8;
  const int a_r0 = (wm * (BM / 2) + fr) * 64;
  const int b_r0 = (wn * 64 + fr) * 64;

  // staging source (inverse-swizzled per-lane global address)
  const int srow8 = l >> 3;                     // row within 8-row window
  const int scol = ((l & 7) ^ srow8) * 8;       // logical chunk = phys ^ row
  const unsigned short* srcA = A + (size_t)(row0 + srow8) * K + scol;
  const unsigned short* srcB = Bt + (size_t)(col0 + srow8) * K + scol;

  const int nt = K >> 6;

  auto stage = [&](int tt, int mat, int win) {
    const unsigned short* s = (mat ? srcB : srcA) + (size_t)win * 8 * K + tt * 64;
    __builtin_amdgcn_global_load_lds(
        (const __attribute__((address_space(1))) void*)s,
        (__attribute__((address_space(3))) void*)(smem + (tt & 1) * BUF_E + mat * A_E + win * 512),
        16, 0, 0);
  };
  // phase staging: ph0 B rows 0-127, ph1 B rows 128-255,
  // ph2 A-early (rows read in next tile's ph0/ph1), ph3 A-late (ph2/ph3)
  auto stage_ph = [&](int tt, int ph) {
    if (ph == 0) { stage(tt, 1, 2 * wid); stage(tt, 1, 2 * wid + 1); }
    else if (ph == 1) { stage(tt, 1, 16 + 2 * wid); stage(tt, 1, 16 + 2 * wid + 1); }
    else if (ph == 2) {
      if constexpr (BM == 256) {
        const int i0 = 2 * wid, i1 = 2 * wid + 1;
        stage(tt, 0, i0 < 8 ? i0 : 8 + i0);     // wins 0-7, 16-23
        stage(tt, 0, i1 < 8 ? i1 : 8 + i1);
      } else {
        stage(tt, 0, wid < 4 ? wid : 4 + wid);  // wins 0-3, 8-11
      }
    } else {
      if constexpr (BM == 256) {
        const int i0 = 2 * wid, i1 = 2 * wid + 1;
        stage(tt, 0, i0 < 8 ? 8 + i0 : 16 + i0); // wins 8-15, 24-31
        stage(tt, 0, i1 < 8 ? 8 + i1 : 16 + i1);
      } else {
        stage(tt, 0, wid < 4 ? 4 + wid : 8 + wid); // wins 4-7, 12-15
      }
    }
  };

  // ---- prologue: stage tile 0 in canonical order; A-late may stay in flight
  stage_ph(0, 0); stage_ph(0, 1); stage_ph(0, 2); stage_ph(0, 3);
  if constexpr (BM == 256) asm volatile("s_waitcnt vmcnt(2)" ::: "memory");
  else                     asm volatile("s_waitcnt vmcnt(1)" ::: "memory");
  __builtin_amdgcn_s_barrier();
  asm volatile("" ::: "memory");

  f32x4 acc[M_REP][4];
#pragma unroll
  for (int m = 0; m < M_REP; ++m)
#pragma unroll
    for (int n = 0; n < 4; ++n) {
      acc[m][n].x = 0.f; acc[m][n].y = 0.f; acc[m][n].z = 0.f; acc[m][n].w = 0.f;
    }
  bf16x8 bfr[4][2];

  for (int tc = 0; tc < nt; ++tc) {
    const int bo = (tc & 1) * BUF_E;
    const bool pf = (tc + 1) < nt;
    const unsigned short* Ab = smem + bo;
    const unsigned short* Bb = smem + bo + A_E;

#pragma unroll
    for (int ph = 0; ph < 4; ++ph) {
      if (ph == 0) {
#pragma unroll
        for (int n = 0; n < 4; ++n) {
          bfr[n][0] = *(const bf16x8*)(Bb + b_r0 + n * 1024 + cx0);
          bfr[n][1] = *(const bf16x8*)(Bb + b_r0 + n * 1024 + cx1);
        }
      }
      bf16x8 af[2][2];
      if constexpr (BM == 256) {
        af[0][0] = *(const bf16x8*)(Ab + a_r0 + (2 * ph) * 1024 + cx0);
        af[0][1] = *(const bf16x8*)(Ab + a_r0 + (2 * ph) * 1024 + cx1);
        af[1][0] = *(const bf16x8*)(Ab + a_r0 + (2 * ph + 1) * 1024 + cx0);
        af[1][1] = *(const bf16x8*)(Ab + a_r0 + (2 * ph + 1) * 1024 + cx1);
      } else {
        af[0][0] = *(const bf16x8*)(Ab + a_r0 + ph * 1024 + cx0);
        af[0][1] = *(const bf16x8*)(Ab + a_r0 + ph * 1024 + cx1);
      }
      if (pf) stage_ph(tc + 1, ph);
      if (ph == 1) {                 // protect A-late(tc) before ph2/ph3 reads
        if (pf) asm volatile("s_waitcnt vmcnt(4)" ::: "memory");
        else    asm volatile("s_waitcnt vmcnt(0)" ::: "memory");
      } else if (ph == 3 && pf) {    // boundary: B + A-early of tc+1 landed
        if constexpr (BM == 256) asm volatile("s_waitcnt vmcnt(2)" ::: "memory");
        else                     asm volatile("s_waitcnt vmcnt(1)" ::: "memory");
      }
      __builtin_amdgcn_s_barrier();
      asm volatile("" ::: "memory");
      __builtin_amdgcn_s_setprio(1);
      if constexpr (BM == 256) {
#pragma unroll
        for (int mm = 0; mm < 2; ++mm)
#pragma unroll
          for (int n = 0; n < 4; ++n) {
            acc[2 * ph + mm][n] = __builtin_amdgcn_mfma_f32_16x16x32_bf16(
                af[mm][0], bfr[n][0], acc[2 * ph + mm][n], 0, 0, 0);
            acc[2 * ph + mm][n] = __builtin_amdgcn_mfma_f32_16x16x32_bf16(
                af[mm][1], bfr[n][1], acc[2 * ph + mm][n], 0, 0, 0);
          }
      } else {
#pragma unroll
        for (int n = 0; n < 4; ++n) {
          acc[ph][n] = __builtin_amdgcn_mfma_f32_16x16x32_bf16(
              af[0][0], bfr[n][0], acc[ph][n], 0, 0, 0);
          acc[ph][n] = __builtin_amdgcn_mfma_f32_16x16x32_bf16(
              af[0][1], bfr[n][1], acc[ph][n], 0, 0, 0);
        }
      }
      __builtin_amdgcn_s_setprio(0);
      __builtin_amdgcn_s_barrier();
      asm volatile("" ::: "memory");
    }
  }

  // ---- epilogue ----
  if constexpr (EPI == 2) {
#pragma unroll
    for (int n = 0; n < 4; ++n) {
      const int col = col0 + wn * 64 + n * 16 + fr;
      const float bi = bias[col];
#pragma unroll
      for (int m = 0; m < M_REP; ++m)
#pragma unroll
        for (int e = 0; e < 4; ++e) {
          const int row = row0 + wm * (BM / 2) + m * 16 + q4 * 4 + e;
          Hres[(size_t)row * N + col] += acc[m][n][e] + bi;
        }
    }
  } else {
    // per-wave repack region: 64 rows x 144 B (16B-aligned pitch)
    char* wreg = (char*)smem + wid * 9216;
    float bi[4];
#pragma unroll
    for (int n = 0; n < 4; ++n) bi[n] = bias[col0 + wn * 64 + n * 16 + fr];
#pragma unroll
    for (int half = 0; half < M_REP / 4; ++half) {
#pragma unroll
      for (int m = 0; m < 4; ++m)
#pragma unroll
        for (int n = 0; n < 4; ++n)
#pragma unroll
          for (int e = 0; e < 4; ++e) {
            float v = acc[half * 4 + m][n][e] + bi[n];
            if (EPI == 1) v = gelu_new(v);
            *(unsigned short*)(wreg + (m * 16 + q4 * 4 + e) * 144 +
                               (n * 16 + fr) * 2) = f2bf(v);
          }
#pragma unroll
      for (int rb = 0; rb < 8; ++rb) {
        const int rowl = rb * 8 + (l >> 3);
        u16x8 vv = *(const u16x8*)(wreg + rowl * 144 + (l & 7) * 16);
        const int rg = row0 + wm * (BM / 2) + half * 64 + rowl;
        *(u16x8*)(Cb + (size_t)rg * N + col0 + wn * 64 + (l & 7) * 8) = vv;
      }
    }
  }
}

// ---------------------------------------------------------------------------
// MFMA flash attention (unchanged; verified round 3/4).
// ---------------------------------------------------------------------------
__global__ __launch_bounds__(256) void attn_mfma(
    const unsigned short* __restrict__ qkv, unsigned short* __restrict__ aout,
    int b0) {
  __shared__ alignas(16) unsigned short Klds[256 * 64];
  __shared__ alignas(16) unsigned short Vt[64 * 256];
  const int bh = blockIdx.x;
  const int bl = bh >> 4, hd = bh & 15;
  const size_t base = (size_t)bl * 256 * 3072 + (size_t)hd * 64;
  const int t = threadIdx.x;
  const int w = t >> 6, l = t & 63;
  const int lq = l & 31, hl = l >> 5;

#pragma unroll
  for (int i = 0; i < 8; ++i) {
    const int r = i * 32 + (t >> 3);
    const int c = t & 7;
    u16x8 kv = *(const u16x8*)(qkv + base + (size_t)r * 3072 + 1024 + c * 8);
    *(u16x8*)(Klds + r * 64 + ((c ^ (r & 7)) * 8)) = kv;
    u16x8 vv = *(const u16x8*)(qkv + base + (size_t)r * 3072 + 2048 + c * 8);
#pragma unroll
    for (int j = 0; j < 8; ++j) {
      const int d = c * 8 + j;
      Vt[d * 256 + (((r >> 3) ^ (d & 31)) * 8) + (r & 7)] = vv[j];
    }
  }

  const int q0 = w * 64;
  bf16x8 qf[2][4];
#pragma unroll
  for (int n = 0; n < 2; ++n)
#pragma unroll
    for (int d16 = 0; d16 < 4; ++d16)
      qf[n][d16] = *(const bf16x8*)(qkv + base +
          (size_t)(q0 + n * 32 + lq) * 3072 + d16 * 16 + hl * 8);
  __syncthreads();

  const float cs = 0.125f * 1.44269504088896f;
  f32x16 O[2][2];
#pragma unroll
  for (int m = 0; m < 2; ++m)
#pragma unroll
    for (int n = 0; n < 2; ++n)
#pragma unroll
      for (int e = 0; e < 16; ++e) O[m][n][e] = 0.f;
  float mrun[2] = {-3.0e38f, -3.0e38f};
  float lrun[2] = {0.f, 0.f};

  const int ktmax = (q0 + 63) >> 5;
  for (int kt = 0; kt <= ktmax; ++kt) {
    bf16x8 kf[4];
    const int krow = kt * 32 + lq;
#pragma unroll
    for (int d16 = 0; d16 < 4; ++d16) {
      const int chunk = (d16 * 2 + hl) ^ (krow & 7);
      kf[d16] = *(const bf16x8*)(Klds + krow * 64 + chunk * 8);
    }
    const int nlo = (kt * 32 > q0 + 31) ? 1 : 0;
    bf16x8 pfrag[2][2];
#pragma unroll
    for (int n = 0; n < 2; ++n) {
      if (n < nlo) continue;
      f32x16 s;
#pragma unroll
      for (int e = 0; e < 16; ++e) s[e] = 0.f;
#pragma unroll
      for (int d16 = 0; d16 < 4; ++d16)
        s = __builtin_amdgcn_mfma_f32_32x32x16_bf16(kf[d16], qf[n][d16], s, 0, 0, 0);
      const int qg = q0 + n * 32 + lq;
      float sv[16];
#pragma unroll
      for (int r = 0; r < 16; ++r) {
        const int kg = kt * 32 + (r & 3) + 8 * (r >> 2) + 4 * hl;
        const float x = s[r] * cs;
        sv[r] = (kg > qg) ? -3.0e38f : x;
      }
      float pmax = sv[0];
#pragma unroll
      for (int r = 1; r < 16; ++r) pmax = fmaxf(pmax, sv[r]);
      pmax = fmaxf(pmax, __shfl_xor(pmax, 32, 64));
      const float nm = fmaxf(mrun[n], pmax);
      const float alpha = exp2f(mrun[n] - nm);
      mrun[n] = nm;
      float psum = 0.f;
#pragma unroll
      for (int r = 0; r < 16; ++r) {
        sv[r] = exp2f(sv[r] - nm);
        psum += sv[r];
      }
      psum += __shfl_xor(psum, 32, 64);
      lrun[n] = lrun[n] * alpha + psum;
#pragma unroll
      for (int m = 0; m < 2; ++m)
#pragma unroll
        for (int e = 0; e < 16; ++e) O[m][n][e] *= alpha;
#pragma unroll
      for (int h = 0; h < 2; ++h) {
        unsigned int a0 = cvtpk(sv[h * 8 + 0], sv[h * 8 + 1]);
        unsigned int a1 = cvtpk(sv[h * 8 + 2], sv[h * 8 + 3]);
        unsigned int c0 = cvtpk(sv[h * 8 + 4], sv[h * 8 + 5]);
        unsigned int c1 = cvtpk(sv[h * 8 + 6], sv[h * 8 + 7]);
        plswap(a0, c0);
        plswap(a1, c1);
        u32x4 fw; fw.x = a0; fw.y = a1; fw.z = c0; fw.w = c1;
        pfrag[n][h] = __builtin_bit_cast(bf16x8, fw);
      }
    }
#pragma unroll
    for (int m = 0; m < 2; ++m)
#pragma unroll
      for (int h = 0; h < 2; ++h) {
        const int dd = m * 32 + lq;
        const int chunk = (kt * 4 + h * 2 + hl) ^ (dd & 31);
        bf16x8 vf = *(const bf16x8*)(Vt + dd * 256 + chunk * 8);
#pragma unroll
        for (int n = 0; n < 2; ++n)
          if (n >= nlo)
            O[m][n] = __builtin_amdgcn_mfma_f32_32x32x16_bf16(vf, pfrag[n][h], O[m][n], 0, 0, 0);
      }
  }

#pragma unroll
  for (int n = 0; n < 2; ++n) {
    const float inv = 1.0f / lrun[n];
    const size_t row = (size_t)(b0 + bl) * 256 + q0 + n * 32 + lq;
#pragma unroll
    for (int m = 0; m < 2; ++m) {
#pragma unroll
      for (int qd = 0; qd < 4; ++qd) {
        u16x4 pk;
#pragma unroll
        for (int e = 0; e < 4; ++e) pk[e] = f2bf(O[m][n][qd * 4 + e] * inv);
        *(u16x4*)(aout + row * 1024 + hd * 64 + m * 32 + qd * 8 + hl * 4) = pk;
      }
    }
  }
}

// ---------------------------------------------------------------------------
// Loss
// ---------------------------------------------------------------------------
__device__ __forceinline__ float block_reduce_sum256(float v) {
#pragma unroll
  for (int off = 32; off; off >>= 1) v += __shfl_xor(v, off, 64);
  __shared__ float red[4];
  const int t = threadIdx.x;
  if ((t & 63) == 0) red[t >> 6] = v;
  __syncthreads();
  return red[0] + red[1] + red[2] + red[3];
}

__global__ __launch_bounds__(256) void loss_partial(
    const float* __restrict__ hf, const float* __restrict__ sent,
    float* __restrict__ part) {
  const int s = blockIdx.x, t = threadIdx.x;
  f32x4 a = ((const f32x4*)(hf + (size_t)s * 1024))[t];
  f32x4 b = ((const f32x4*)(sent + (size_t)(s + 1) * 1024))[t];
  f32x4 d = a - b;
  float v = d.x * d.x + d.y * d.y + d.z * d.z + d.w * d.w;
  float tot = block_reduce_sum256(v);
  if (t == 0) part[s] = tot;
}

__global__ __launch_bounds__(256) void loss_final(
    const float* __restrict__ part, float* __restrict__ out) {
  const int t = threadIdx.x;
  float v = (t < 255) ? part[t] : 0.f;
  float s = block_reduce_sum256(v);
  if (t == 0) out[0] = s * (1.0f / (255.0f * 1024.0f));
}

// ---------------------------------------------------------------------------
// Workspace layout (bytes) — total ~120 MiB
// ---------------------------------------------------------------------------
constexpr size_t OFF_X     = 0;
constexpr size_t OFF_QKV   = 33554432;
constexpr size_t OFF_WQKV  = OFF_QKV + 67108864;
constexpr size_t OFF_WPROJ = OFF_WQKV + 6291456;
constexpr size_t OFF_WFC   = OFF_WPROJ + 2097152;
constexpr size_t OFF_WMLP  = OFF_WFC + 8388608;
constexpr size_t OFF_PART  = OFF_WMLP + 8388608;

extern "C" void kernel_launch(void* const* d_in, const int* in_sizes, int n_in,
                              void* d_out, int out_size, void* d_ws, size_t ws_size,
                              hipStream_t stream) {
  (void)in_sizes; (void)n_in; (void)out_size; (void)ws_size;
  const float* sent    = (const float*)d_in[0];
  const float* wpe     = (const float*)d_in[1];
  const float* ln1_g   = (const float*)d_in[2];
  const float* ln1_b   = (const float*)d_in[3];
  const float* attn_w  = (const float*)d_in[4];
  const float* attn_b  = (const float*)d_in[5];
  const float* attn_pw = (const float*)d_in[6];
  const float* attn_pb = (const float*)d_in[7];
  const float* ln2_g   = (const float*)d_in[8];
  const float* ln2_b   = (const float*)d_in[9];
  const float* fc_w    = (const float*)d_in[10];
  const float* fc_b    = (const float*)d_in[11];
  const float* mlp_w   = (const float*)d_in[12];
  const float* mlp_b   = (const float*)d_in[13];
  const float* lnf_g   = (const float*)d_in[14];
  const float* lnf_b   = (const float*)d_in[15];
  float* out_h = (float*)d_out;

  char* ws = (char*)d_ws;
  float* h              = out_h;
  unsigned short* xb    = (unsigned short*)(ws + OFF_X);
  unsigned short* qkvb  = (unsigned short*)(ws + OFF_QKV);
  unsigned short* mb    = (unsigned short*)(ws + OFF_QKV);
  unsigned short* wqkv  = (unsigned short*)(ws + OFF_WQKV);
  unsigned short* wproj = (unsigned short*)(ws + OFF_WPROJ);
  unsigned short* wfc   = (unsigned short*)(ws + OFF_WFC);
  unsigned short* wmlp  = (unsigned short*)(ws + OFF_WMLP);
  float* part           = (float*)(ws + OFF_PART);

  add_wpe_kernel<<<16384, 256, 0, stream>>>(sent, wpe, h);

  const dim3 tb(32, 8, 1);
  for (int i = 0; i < 2; ++i) {
    transpose_bf16<<<dim3(96, 32), tb, 0, stream>>>(
        attn_w + (size_t)i * 1024 * 3072, wqkv, 1024, 3072);
    transpose_bf16<<<dim3(32, 32), tb, 0, stream>>>(
        attn_pw + (size_t)i * 1024 * 1024, wproj, 1024, 1024);
    transpose_bf16<<<dim3(128, 32), tb, 0, stream>>>(
        fc_w + (size_t)i * 1024 * 4096, wfc, 1024, 4096);
    transpose_bf16<<<dim3(32, 128), tb, 0, stream>>>(
        mlp_w + (size_t)i * 4096 * 1024, wmlp, 4096, 1024);

    // --- attention block ---
    ln_kernel<0><<<16384, 256, 0, stream>>>(h, ln1_g + i * 1024, ln1_b + i * 1024, xb);
    for (int c = 0; c < 2; ++c) {   // 8192-row (32-batch) chunks
      const size_t r0 = (size_t)c * 8192;
      gemm8p<256, 0><<<384, 512, 0, stream>>>(
          xb + r0 * 1024, wqkv, attn_b + i * 3072, qkvb, nullptr, 3072, 1024, 12, 32);
      attn_mfma<<<512, 256, 0, stream>>>(qkvb, xb, c * 32);  // ab aliases xb
    }
    gemm8p<256, 2><<<256, 512, 0, stream>>>(
        xb, wproj, attn_pb + i * 1024, nullptr, h, 1024, 1024, 4, 64);

    // --- MLP block ---
    ln_kernel<0><<<16384, 256, 0, stream>>>(h, ln2_g + i * 1024, ln2_b + i * 1024, xb);
    for (int c = 0; c < 2; ++c) {
      const size_t r0 = (size_t)c * 8192;
      gemm8p<256, 1><<<512, 512, 0, stream>>>(
          xb + r0 * 1024, wfc, fc_b + i * 4096, mb, nullptr, 4096, 1024, 16, 32);
      gemm8p<128, 2><<<256, 512, 0, stream>>>(
          mb, wmlp, mlp_b + i * 1024, nullptr, h + r0 * 1024, 1024, 4096, 4, 64);
    }
  }

  ln_kernel<1><<<16384, 256, 0, stream>>>(h, lnf_g, lnf_b, out_h);
  loss_partial<<<255, 256, 0, stream>>>(out_h, sent, part);
  loss_final<<<1, 256, 0, stream>>>(part, out_h + 16777216);
}

// Round 6
// 1257.232 us; speedup vs baseline: 2.2670x; 1.0475x over previous
//
#include <hip/hip_runtime.h>
#include <cstdint>
#include <cstddef>

// ---------------------------------------------------------------------------
// Model dims (fixed): B=64 S=256 E=1024 H=16 D=64 NL=2 FF=4096; T=16384 rows.
// h (residual stream, f32) lives in d_out. Workspace budget ~120 MiB.
// ---------------------------------------------------------------------------

typedef __attribute__((ext_vector_type(4))) float f32x4;
typedef __attribute__((ext_vector_type(16))) float f32x16;
typedef __attribute__((ext_vector_type(8))) __bf16 bf16x8;
typedef __attribute__((ext_vector_type(4))) unsigned int u32x4;
typedef __attribute__((ext_vector_type(8))) unsigned short u16x8;
typedef __attribute__((ext_vector_type(4))) unsigned short u16x4;

__device__ __forceinline__ unsigned short f2bf(float x) {
  unsigned int u = __builtin_bit_cast(unsigned int, x);
  u += 0x7fffu + ((u >> 16) & 1u);          // RNE
  return (unsigned short)(u >> 16);
}
__device__ __forceinline__ float gelu_new(float x) {
  // 0.5x(1+tanh(u)) == x * sigmoid(2u), u = 0.79788456(x + 0.044715 x^3)
  float u = 0.7978845608028654f * (x + 0.044715f * x * x * x);
  return x * __builtin_amdgcn_rcpf(1.0f + __expf(-2.0f * u));
}
__device__ __forceinline__ unsigned int cvtpk(float lo, float hi) {
  unsigned int r;
  asm("v_cvt_pk_bf16_f32 %0, %1, %2" : "=v"(r) : "v"(lo), "v"(hi));
  return r;
}
__device__ __forceinline__ void plswap(unsigned int& a, unsigned int& b) {
  asm("v_permlane32_swap_b32 %0, %1" : "+v"(a), "+v"(b));
}

// ---------------------------------------------------------------------------
// Weight convert+transpose: W f32 [K,N] -> Wt bf16 [N,K]
// ---------------------------------------------------------------------------
__global__ __launch_bounds__(256) void transpose_bf16(
    const float* __restrict__ W, unsigned short* __restrict__ Wt, int K, int N) {
  __shared__ float tile[32][33];
  const int n0 = blockIdx.x * 32, k0 = blockIdx.y * 32;
  const int tx = threadIdx.x, ty = threadIdx.y;
#pragma unroll
  for (int j = 0; j < 32; j += 8)
    tile[ty + j][tx] = W[(size_t)(k0 + ty + j) * N + n0 + tx];
  __syncthreads();
#pragma unroll
  for (int j = 0; j < 32; j += 8)
    Wt[(size_t)(n0 + ty + j) * K + k0 + tx] = f2bf(tile[tx][ty + j]);
}

// ---------------------------------------------------------------------------
// LayerNorm over E=1024: one block per row.
// MODE 0: bf16 out;  MODE 1: f32 out (final LN, in-place safe)
// ---------------------------------------------------------------------------
__device__ __forceinline__ void ln_core(
    f32x4 v, const float* g, const float* bb, int row, int t,
    int outf32, void* outp) {
  float s = v.x + v.y + v.z + v.w;
  float sq = v.x * v.x + v.y * v.y + v.z * v.z + v.w * v.w;
#pragma unroll
  for (int off = 32; off; off >>= 1) {
    s += __shfl_xor(s, off, 64);
    sq += __shfl_xor(sq, off, 64);
  }
  __shared__ float red[8];
  if ((t & 63) == 0) { red[t >> 6] = s; red[4 + (t >> 6)] = sq; }
  __syncthreads();
  s = red[0] + red[1] + red[2] + red[3];
  sq = red[4] + red[5] + red[6] + red[7];
  const float mean = s * (1.0f / 1024.0f);
  const float var = sq * (1.0f / 1024.0f) - mean * mean;
  const float rs = rsqrtf(var + 1e-5f);
  const f32x4 gv = ((const f32x4*)g)[t];
  const f32x4 bv = ((const f32x4*)bb)[t];
  float y0 = (v.x - mean) * rs * gv.x + bv.x;
  float y1 = (v.y - mean) * rs * gv.y + bv.y;
  float y2 = (v.z - mean) * rs * gv.z + bv.z;
  float y3 = (v.w - mean) * rs * gv.w + bv.w;
  if (outf32) {
    f32x4 o; o.x = y0; o.y = y1; o.z = y2; o.w = y3;
    ((f32x4*)outp)[(size_t)row * 256 + t] = o;
  } else {
    u16x4 pk;
    pk.x = f2bf(y0); pk.y = f2bf(y1); pk.z = f2bf(y2); pk.w = f2bf(y3);
    ((u16x4*)outp)[(size_t)row * 256 + t] = pk;
  }
}

template <int OUTF32>
__global__ __launch_bounds__(256) void ln_kernel(
    const float* __restrict__ hin, const float* __restrict__ g,
    const float* __restrict__ bb, void* __restrict__ outp) {
  const int row = blockIdx.x, t = threadIdx.x;
  const f32x4 v = ((const f32x4*)(hin + (size_t)row * 1024))[t];
  ln_core(v, g, bb, row, t, OUTF32, outp);
}

// fused: h = sent + wpe[s];  xb = LN(h)
__global__ __launch_bounds__(256) void ln_wpe_kernel(
    const float* __restrict__ sent, const float* __restrict__ wpe,
    const float* __restrict__ g, const float* __restrict__ bb,
    float* __restrict__ h, unsigned short* __restrict__ xb) {
  const int row = blockIdx.x, t = threadIdx.x;
  const int s = row & 255;
  f32x4 a = ((const f32x4*)(sent + (size_t)row * 1024))[t];
  f32x4 w = ((const f32x4*)(wpe + (size_t)s * 1024))[t];
  f32x4 v = a + w;
  ((f32x4*)(h + (size_t)row * 1024))[t] = v;
  ln_core(v, g, bb, row, t, 0, xb);
}

// ---------------------------------------------------------------------------
// Pipelined GEMM: C[M,N] = A[M,K](bf16) * Bt[N,K](bf16)^T (+bias)
// BM x 256 tile, BK=64, 8 waves (2m x 4n), 512 thr, LDS 2x double-buffer.
// TWO {counted-vmcnt + raw s_barrier} per K-tile (never vmcnt(0) mid-loop):
//   half0: read B-all + A m-lo frags | stage B(tc+1) | 32/16 MFMA | vmcnt | bar
//   half1: read A m-hi frags         | stage A(tc+1) | 32/16 MFMA | vmcnt | bar
// chunk^row XOR LDS swizzle (conflict-free), setprio around MFMA clusters,
// XCD-chunk + 4-wide-stripe block swizzle.
// BM=128 uses a permuted A slot order so A-late forms a stageable set:
//   slot(r: wm*64+m*16+fr) = (m>>1)*64 + wm*32 + (m&1)*16 + fr
// EPI: 0 = bf16 (+bias), 1 = bf16 gelu(+bias), 2 = f32 residual +=
// Epilogue (EPI 0/1): LDS repack (pitch 144B) -> coalesced u16x8 stores.
// Requires: M%BM==0, N%256==0, K%64==0, nt>=2, (gx*gy)%8==0, gx%4==0.
// ---------------------------------------------------------------------------
template <int BM, int EPI>
__global__ __launch_bounds__(512, 2) void gemm8p(
    const unsigned short* __restrict__ A, const unsigned short* __restrict__ Bt,
    const float* __restrict__ bias, unsigned short* __restrict__ Cb,
    float* __restrict__ Hres, int N, int K, int gx, int gy) {
  constexpr int M_REP = BM / 32;           // 8 or 4
  constexpr int MH = M_REP / 2;            // frags per half
  constexpr int A_E = BM * 64;             // A elems per K-tile
  constexpr int BUF_E = A_E + 16384;       // + B (256x64)
  __shared__ alignas(16) unsigned short smem[2 * BUF_E];

  // ---- block swizzle: XCD chunk (bijective) + 4-wide bx stripes ----
  const int nwg = gx * gy;
  const int dd = blockIdx.x;
  const int wrk = (dd & 7) * (nwg >> 3) + (dd >> 3);
  const int stripe = gy * 4;
  const int cg = wrk / stripe;
  const int rem = wrk - cg * stripe;
  const int by = rem >> 2;
  const int bx = cg * 4 + (rem & 3);
  const int row0 = by * BM, col0 = bx * 256;

  const int t = threadIdx.x;
  const int wid = t >> 6, l = t & 63;
  const int wm = wid >> 2, wn = wid & 3;
  const int fr = l & 15, q4 = l >> 4;

  // frag-read: chunk (kk*4+q4) ^ (row&7); row%8 == fr&7 for all frag rows
  const int cx0 = (q4 ^ (fr & 7)) * 8;
  const int cx1 = ((4 + q4) ^ (fr & 7)) * 8;
  const int b_r0 = (wn * 64 + fr) * 64;
  // A frag slot (elements) for frag index m
  auto a_slot = [&](int m) -> int {
    if constexpr (BM == 256) return (wm * 128 + m * 16 + fr) * 64;
    else return ((m >> 1) * 64 + wm * 32 + (m & 1) * 16 + fr) * 64;
  };

  // ---- staging (inverse-swizzled per-lane global source, linear LDS dest) --
  const int lrow = l >> 3;                      // row within 8-row win
  const int scol = ((l & 7) ^ (lrow & 7)) * 8;  // logical chunk = phys ^ row

  auto stB = [&](int tt, int win) {             // win 0..31, rows win*8..+8
    const unsigned short* s =
        Bt + (size_t)(col0 + win * 8 + lrow) * K + tt * 64 + scol;
    __builtin_amdgcn_global_load_lds(
        (const __attribute__((address_space(1))) void*)s,
        (__attribute__((address_space(3))) void*)(smem + (tt & 1) * BUF_E + A_E + win * 512),
        16, 0, 0);
  };
  auto stA = [&](int tt, int win) {             // win 0..BM/8-1 (slot order)
    int rb;
    if constexpr (BM == 256) rb = win * 8;
    else rb = ((win >> 2) & 1) * 64 + (win >> 3) * 32 + (win & 3) * 8;
    const unsigned short* s =
        A + (size_t)(row0 + rb + lrow) * K + tt * 64 + scol;
    __builtin_amdgcn_global_load_lds(
        (const __attribute__((address_space(1))) void*)s,
        (__attribute__((address_space(3))) void*)(smem + (tt & 1) * BUF_E + win * 512),
        16, 0, 0);
  };
  // stage sets (per-thread load counts):
  //   B-set (half0): 4 loads (wins 2wid,2wid+1,16+2wid,16+2wid+1)
  //   A-set (half1): BM=256 -> 4 loads (early wins then late wins);
  //                  BM=128 -> 2 loads (TA0 win=wid [m0-1], TA1 win=8+wid [m2-3])
  auto stageB_set = [&](int tt) {
    stB(tt, 2 * wid); stB(tt, 2 * wid + 1);
    stB(tt, 16 + 2 * wid); stB(tt, 16 + 2 * wid + 1);
  };
  auto stageA_set = [&](int tt) {
    if constexpr (BM == 256) {
      const int i0 = 2 * wid, i1 = 2 * wid + 1;
      stA(tt, i0 < 8 ? i0 : 8 + i0);      // A-early: wins 0-7,16-23 (m0-3)
      stA(tt, i1 < 8 ? i1 : 8 + i1);
      stA(tt, i0 < 8 ? 8 + i0 : 16 + i0); // A-late: wins 8-15,24-31 (m4-7)
      stA(tt, i1 < 8 ? 8 + i1 : 16 + i1);
    } else {
      stA(tt, wid);                       // TA0: slots 0-63 (m0-1 rows)
      stA(tt, 8 + wid);                   // TA1: slots 64-127 (m2-3 rows)
    }
  };
  // in-flight accounting (per thread):
  //   boundary: A-late(tc+1) may fly -> vmcnt(2) [BM=256] / vmcnt(1) [BM=128]
  //   mid-tile: B(tc+1) (4 loads) may fly, A-late(tc) must land -> vmcnt(4)
  constexpr int VM_BOUND = (BM == 256) ? 2 : 1;

  const int nt = K >> 6;

  // ---- prologue: stage tile 0 ----
  stageB_set(0);
  stageA_set(0);
  asm volatile("s_waitcnt vmcnt(%0)" :: "i"(VM_BOUND) : "memory");
  __builtin_amdgcn_s_barrier();
  asm volatile("" ::: "memory");

  f32x4 acc[M_REP][4];
#pragma unroll
  for (int m = 0; m < M_REP; ++m)
#pragma unroll
    for (int n = 0; n < 4; ++n) {
      acc[m][n].x = 0.f; acc[m][n].y = 0.f; acc[m][n].z = 0.f; acc[m][n].w = 0.f;
    }

  for (int tc = 0; tc < nt; ++tc) {
    const unsigned short* Ab = smem + (tc & 1) * BUF_E;
    const unsigned short* Bb = Ab + A_E;
    const bool pf = (tc + 1) < nt;

    // ================= half 0: B-all + A m-lo =================
    bf16x8 bfr[4][2], af[MH][2];
#pragma unroll
    for (int n = 0; n < 4; ++n) {
      bfr[n][0] = *(const bf16x8*)(Bb + b_r0 + n * 1024 + cx0);
      bfr[n][1] = *(const bf16x8*)(Bb + b_r0 + n * 1024 + cx1);
    }
#pragma unroll
    for (int m = 0; m < MH; ++m) {
      af[m][0] = *(const bf16x8*)(Ab + a_slot(m) + cx0);
      af[m][1] = *(const bf16x8*)(Ab + a_slot(m) + cx1);
    }
    if (pf) stageB_set(tc + 1);
    __builtin_amdgcn_s_setprio(1);
#pragma unroll
    for (int m = 0; m < MH; ++m)
#pragma unroll
      for (int n = 0; n < 4; ++n) {
        acc[m][n] = __builtin_amdgcn_mfma_f32_16x16x32_bf16(
            af[m][0], bfr[n][0], acc[m][n], 0, 0, 0);
        acc[m][n] = __builtin_amdgcn_mfma_f32_16x16x32_bf16(
            af[m][1], bfr[n][1], acc[m][n], 0, 0, 0);
      }
    __builtin_amdgcn_s_setprio(0);
    if (pf) asm volatile("s_waitcnt vmcnt(4)" ::: "memory");
    else    asm volatile("s_waitcnt vmcnt(0)" ::: "memory");
    __builtin_amdgcn_s_barrier();
    asm volatile("" ::: "memory");

    // ================= half 1: A m-hi =================
    bf16x8 ah[MH][2];
#pragma unroll
    for (int m = 0; m < MH; ++m) {
      ah[m][0] = *(const bf16x8*)(Ab + a_slot(MH + m) + cx0);
      ah[m][1] = *(const bf16x8*)(Ab + a_slot(MH + m) + cx1);
    }
    if (pf) stageA_set(tc + 1);
    __builtin_amdgcn_s_setprio(1);
#pragma unroll
    for (int m = 0; m < MH; ++m)
#pragma unroll
      for (int n = 0; n < 4; ++n) {
        acc[MH + m][n] = __builtin_amdgcn_mfma_f32_16x16x32_bf16(
            ah[m][0], bfr[n][0], acc[MH + m][n], 0, 0, 0);
        acc[MH + m][n] = __builtin_amdgcn_mfma_f32_16x16x32_bf16(
            ah[m][1], bfr[n][1], acc[MH + m][n], 0, 0, 0);
      }
    __builtin_amdgcn_s_setprio(0);
    if (pf) asm volatile("s_waitcnt vmcnt(%0)" :: "i"(VM_BOUND) : "memory");
    else    asm volatile("s_waitcnt vmcnt(0)" ::: "memory");
    __builtin_amdgcn_s_barrier();
    asm volatile("" ::: "memory");
  }

  // ---- epilogue ----
  if constexpr (EPI == 2) {
#pragma unroll
    for (int n = 0; n < 4; ++n) {
      const int col = col0 + wn * 64 + n * 16 + fr;
      const float bi = bias[col];
#pragma unroll
      for (int m = 0; m < M_REP; ++m)
#pragma unroll
        for (int e = 0; e < 4; ++e) {
          const int row = row0 + wm * (BM / 2) + m * 16 + q4 * 4 + e;
          Hres[(size_t)row * N + col] += acc[m][n][e] + bi;
        }
    }
  } else {
    // per-wave repack region: 64 rows x 144 B (16B-aligned pitch)
    char* wreg = (char*)smem + wid * 9216;
    float bi[4];
#pragma unroll
    for (int n = 0; n < 4; ++n) bi[n] = bias[col0 + wn * 64 + n * 16 + fr];
#pragma unroll
    for (int half = 0; half < M_REP / 4; ++half) {
#pragma unroll
      for (int m = 0; m < 4; ++m)
#pragma unroll
        for (int n = 0; n < 4; ++n)
#pragma unroll
          for (int e = 0; e < 4; ++e) {
            float v = acc[half * 4 + m][n][e] + bi[n];
            if (EPI == 1) v = gelu_new(v);
            *(unsigned short*)(wreg + (m * 16 + q4 * 4 + e) * 144 +
                               (n * 16 + fr) * 2) = f2bf(v);
          }
#pragma unroll
      for (int rb = 0; rb < 8; ++rb) {
        const int rowl = rb * 8 + (l >> 3);
        u16x8 vv = *(const u16x8*)(wreg + rowl * 144 + (l & 7) * 16);
        const int rg = row0 + wm * (BM / 2) + half * 64 + rowl;
        *(u16x8*)(Cb + (size_t)rg * N + col0 + wn * 64 + (l & 7) * 8) = vv;
      }
    }
  }
}

// ---------------------------------------------------------------------------
// MFMA flash attention (unchanged; verified rounds 3-5).
// ---------------------------------------------------------------------------
__global__ __launch_bounds__(256) void attn_mfma(
    const unsigned short* __restrict__ qkv, unsigned short* __restrict__ aout,
    int b0) {
  __shared__ alignas(16) unsigned short Klds[256 * 64];
  __shared__ alignas(16) unsigned short Vt[64 * 256];
  const int bh = blockIdx.x;
  const int bl = bh >> 4, hd = bh & 15;
  const size_t base = (size_t)bl * 256 * 3072 + (size_t)hd * 64;
  const int t = threadIdx.x;
  const int w = t >> 6, l = t & 63;
  const int lq = l & 31, hl = l >> 5;

#pragma unroll
  for (int i = 0; i < 8; ++i) {
    const int r = i * 32 + (t >> 3);
    const int c = t & 7;
    u16x8 kv = *(const u16x8*)(qkv + base + (size_t)r * 3072 + 1024 + c * 8);
    *(u16x8*)(Klds + r * 64 + ((c ^ (r & 7)) * 8)) = kv;
    u16x8 vv = *(const u16x8*)(qkv + base + (size_t)r * 3072 + 2048 + c * 8);
#pragma unroll
    for (int j = 0; j < 8; ++j) {
      const int d = c * 8 + j;
      Vt[d * 256 + (((r >> 3) ^ (d & 31)) * 8) + (r & 7)] = vv[j];
    }
  }

  const int q0 = w * 64;
  bf16x8 qf[2][4];
#pragma unroll
  for (int n = 0; n < 2; ++n)
#pragma unroll
    for (int d16 = 0; d16 < 4; ++d16)
      qf[n][d16] = *(const bf16x8*)(qkv + base +
          (size_t)(q0 + n * 32 + lq) * 3072 + d16 * 16 + hl * 8);
  __syncthreads();

  const float cs = 0.125f * 1.44269504088896f;
  f32x16 O[2][2];
#pragma unroll
  for (int m = 0; m < 2; ++m)
#pragma unroll
    for (int n = 0; n < 2; ++n)
#pragma unroll
      for (int e = 0; e < 16; ++e) O[m][n][e] = 0.f;
  float mrun[2] = {-3.0e38f, -3.0e38f};
  float lrun[2] = {0.f, 0.f};

  const int ktmax = (q0 + 63) >> 5;
  for (int kt = 0; kt <= ktmax; ++kt) {
    bf16x8 kf[4];
    const int krow = kt * 32 + lq;
#pragma unroll
    for (int d16 = 0; d16 < 4; ++d16) {
      const int chunk = (d16 * 2 + hl) ^ (krow & 7);
      kf[d16] = *(const bf16x8*)(Klds + krow * 64 + chunk * 8);
    }
    const int nlo = (kt * 32 > q0 + 31) ? 1 : 0;
    bf16x8 pfrag[2][2];
#pragma unroll
    for (int n = 0; n < 2; ++n) {
      if (n < nlo) continue;
      f32x16 s;
#pragma unroll
      for (int e = 0; e < 16; ++e) s[e] = 0.f;
#pragma unroll
      for (int d16 = 0; d16 < 4; ++d16)
        s = __builtin_amdgcn_mfma_f32_32x32x16_bf16(kf[d16], qf[n][d16], s, 0, 0, 0);
      const int qg = q0 + n * 32 + lq;
      float sv[16];
#pragma unroll
      for (int r = 0; r < 16; ++r) {
        const int kg = kt * 32 + (r & 3) + 8 * (r >> 2) + 4 * hl;
        const float x = s[r] * cs;
        sv[r] = (kg > qg) ? -3.0e38f : x;
      }
      float pmax = sv[0];
#pragma unroll
      for (int r = 1; r < 16; ++r) pmax = fmaxf(pmax, sv[r]);
      pmax = fmaxf(pmax, __shfl_xor(pmax, 32, 64));
      const float nm = fmaxf(mrun[n], pmax);
      const float alpha = exp2f(mrun[n] - nm);
      mrun[n] = nm;
      float psum = 0.f;
#pragma unroll
      for (int r = 0; r < 16; ++r) {
        sv[r] = exp2f(sv[r] - nm);
        psum += sv[r];
      }
      psum += __shfl_xor(psum, 32, 64);
      lrun[n] = lrun[n] * alpha + psum;
#pragma unroll
      for (int m = 0; m < 2; ++m)
#pragma unroll
        for (int e = 0; e < 16; ++e) O[m][n][e] *= alpha;
#pragma unroll
      for (int h = 0; h < 2; ++h) {
        unsigned int a0 = cvtpk(sv[h * 8 + 0], sv[h * 8 + 1]);
        unsigned int a1 = cvtpk(sv[h * 8 + 2], sv[h * 8 + 3]);
        unsigned int c0 = cvtpk(sv[h * 8 + 4], sv[h * 8 + 5]);
        unsigned int c1 = cvtpk(sv[h * 8 + 6], sv[h * 8 + 7]);
        plswap(a0, c0);
        plswap(a1, c1);
        u32x4 fw; fw.x = a0; fw.y = a1; fw.z = c0; fw.w = c1;
        pfrag[n][h] = __builtin_bit_cast(bf16x8, fw);
      }
    }
#pragma unroll
    for (int m = 0; m < 2; ++m)
#pragma unroll
      for (int h = 0; h < 2; ++h) {
        const int dd = m * 32 + lq;
        const int chunk = (kt * 4 + h * 2 + hl) ^ (dd & 31);
        bf16x8 vf = *(const bf16x8*)(Vt + dd * 256 + chunk * 8);
#pragma unroll
        for (int n = 0; n < 2; ++n)
          if (n >= nlo)
            O[m][n] = __builtin_amdgcn_mfma_f32_32x32x16_bf16(vf, pfrag[n][h], O[m][n], 0, 0, 0);
      }
  }

#pragma unroll
  for (int n = 0; n < 2; ++n) {
    const float inv = 1.0f / lrun[n];
    const size_t row = (size_t)(b0 + bl) * 256 + q0 + n * 32 + lq;
#pragma unroll
    for (int m = 0; m < 2; ++m) {
#pragma unroll
      for (int qd = 0; qd < 4; ++qd) {
        u16x4 pk;
#pragma unroll
        for (int e = 0; e < 4; ++e) pk[e] = f2bf(O[m][n][qd * 4 + e] * inv);
        *(u16x4*)(aout + row * 1024 + hd * 64 + m * 32 + qd * 8 + hl * 4) = pk;
      }
    }
  }
}

// ---------------------------------------------------------------------------
// Loss
// ---------------------------------------------------------------------------
__device__ __forceinline__ float block_reduce_sum256(float v) {
#pragma unroll
  for (int off = 32; off; off >>= 1) v += __shfl_xor(v, off, 64);
  __shared__ float red[4];
  const int t = threadIdx.x;
  if ((t & 63) == 0) red[t >> 6] = v;
  __syncthreads();
  return red[0] + red[1] + red[2] + red[3];
}

__global__ __launch_bounds__(256) void loss_partial(
    const float* __restrict__ hf, const float* __restrict__ sent,
    float* __restrict__ part) {
  const int s = blockIdx.x, t = threadIdx.x;
  f32x4 a = ((const f32x4*)(hf + (size_t)s * 1024))[t];
  f32x4 b = ((const f32x4*)(sent + (size_t)(s + 1) * 1024))[t];
  f32x4 d = a - b;
  float v = d.x * d.x + d.y * d.y + d.z * d.z + d.w * d.w;
  float tot = block_reduce_sum256(v);
  if (t == 0) part[s] = tot;
}

__global__ __launch_bounds__(256) void loss_final(
    const float* __restrict__ part, float* __restrict__ out) {
  const int t = threadIdx.x;
  float v = (t < 255) ? part[t] : 0.f;
  float s = block_reduce_sum256(v);
  if (t == 0) out[0] = s * (1.0f / (255.0f * 1024.0f));
}

// ---------------------------------------------------------------------------
// Workspace layout (bytes) — total ~120 MiB
// ---------------------------------------------------------------------------
constexpr size_t OFF_X     = 0;
constexpr size_t OFF_QKV   = 33554432;
constexpr size_t OFF_WQKV  = OFF_QKV + 67108864;
constexpr size_t OFF_WPROJ = OFF_WQKV + 6291456;
constexpr size_t OFF_WFC   = OFF_WPROJ + 2097152;
constexpr size_t OFF_WMLP  = OFF_WFC + 8388608;
constexpr size_t OFF_PART  = OFF_WMLP + 8388608;

extern "C" void kernel_launch(void* const* d_in, const int* in_sizes, int n_in,
                              void* d_out, int out_size, void* d_ws, size_t ws_size,
                              hipStream_t stream) {
  (void)in_sizes; (void)n_in; (void)out_size; (void)ws_size;
  const float* sent    = (const float*)d_in[0];
  const float* wpe     = (const float*)d_in[1];
  const float* ln1_g   = (const float*)d_in[2];
  const float* ln1_b   = (const float*)d_in[3];
  const float* attn_w  = (const float*)d_in[4];
  const float* attn_b  = (const float*)d_in[5];
  const float* attn_pw = (const float*)d_in[6];
  const float* attn_pb = (const float*)d_in[7];
  const float* ln2_g   = (const float*)d_in[8];
  const float* ln2_b   = (const float*)d_in[9];
  const float* fc_w    = (const float*)d_in[10];
  const float* fc_b    = (const float*)d_in[11];
  const float* mlp_w   = (const float*)d_in[12];
  const float* mlp_b   = (const float*)d_in[13];
  const float* lnf_g   = (const float*)d_in[14];
  const float* lnf_b   = (const float*)d_in[15];
  float* out_h = (float*)d_out;

  char* ws = (char*)d_ws;
  float* h              = out_h;
  unsigned short* xb    = (unsigned short*)(ws + OFF_X);
  unsigned short* qkvb  = (unsigned short*)(ws + OFF_QKV);
  unsigned short* mb    = (unsigned short*)(ws + OFF_QKV);
  unsigned short* wqkv  = (unsigned short*)(ws + OFF_WQKV);
  unsigned short* wproj = (unsigned short*)(ws + OFF_WPROJ);
  unsigned short* wfc   = (unsigned short*)(ws + OFF_WFC);
  unsigned short* wmlp  = (unsigned short*)(ws + OFF_WMLP);
  float* part           = (float*)(ws + OFF_PART);

  const dim3 tb(32, 8, 1);
  for (int i = 0; i < 2; ++i) {
    transpose_bf16<<<dim3(96, 32), tb, 0, stream>>>(
        attn_w + (size_t)i * 1024 * 3072, wqkv, 1024, 3072);
    transpose_bf16<<<dim3(32, 32), tb, 0, stream>>>(
        attn_pw + (size_t)i * 1024 * 1024, wproj, 1024, 1024);
    transpose_bf16<<<dim3(128, 32), tb, 0, stream>>>(
        fc_w + (size_t)i * 1024 * 4096, wfc, 1024, 4096);
    transpose_bf16<<<dim3(32, 128), tb, 0, stream>>>(
        mlp_w + (size_t)i * 4096 * 1024, wmlp, 4096, 1024);

    // --- attention block ---
    if (i == 0)
      ln_wpe_kernel<<<16384, 256, 0, stream>>>(sent, wpe, ln1_g, ln1_b, h, xb);
    else
      ln_kernel<0><<<16384, 256, 0, stream>>>(h, ln1_g + i * 1024, ln1_b + i * 1024, xb);
    for (int c = 0; c < 2; ++c) {   // 8192-row (32-batch) chunks
      const size_t r0 = (size_t)c * 8192;
      gemm8p<256, 0><<<384, 512, 0, stream>>>(
          xb + r0 * 1024, wqkv, attn_b + i * 3072, qkvb, nullptr, 3072, 1024, 12, 32);
      attn_mfma<<<512, 256, 0, stream>>>(qkvb, xb, c * 32);  // ab aliases xb
    }
    gemm8p<256, 2><<<256, 512, 0, stream>>>(
        xb, wproj, attn_pb + i * 1024, nullptr, h, 1024, 1024, 4, 64);

    // --- MLP block ---
    ln_kernel<0><<<16384, 256, 0, stream>>>(h, ln2_g + i * 1024, ln2_b + i * 1024, xb);
    for (int c = 0; c < 2; ++c) {
      const size_t r0 = (size_t)c * 8192;
      gemm8p<256, 1><<<512, 512, 0, stream>>>(
          xb + r0 * 1024, wfc, fc_b + i * 4096, mb, nullptr, 4096, 1024, 16, 32);
      gemm8p<128, 2><<<256, 512, 0, stream>>>(
          mb, wmlp, mlp_b + i * 1024, nullptr, h + r0 * 1024, 1024, 4096, 4, 64);
    }
  }

  ln_kernel<1><<<16384, 256, 0, stream>>>(h, lnf_g, lnf_b, out_h);
  loss_partial<<<255, 256, 0, stream>>>(out_h, sent, part);
  loss_final<<<1, 256, 0, stream>>>(part, out_h + 16777216);
}

// Round 7
// 1189.116 us; speedup vs baseline: 2.3969x; 1.0573x over previous
//
#include <hip/hip_runtime.h>
#include <cstdint>
#include <cstddef>

// ---------------------------------------------------------------------------
// Model dims (fixed): B=64 S=256 E=1024 H=16 D=64 NL=2 FF=4096; T=16384 rows.
// h (residual stream, f32) lives in d_out.
// ---------------------------------------------------------------------------

typedef __attribute__((ext_vector_type(4))) float f32x4;
typedef __attribute__((ext_vector_type(16))) float f32x16;
typedef __attribute__((ext_vector_type(8))) __bf16 bf16x8;
typedef __attribute__((ext_vector_type(4))) unsigned int u32x4;
typedef __attribute__((ext_vector_type(8))) unsigned short u16x8;
typedef __attribute__((ext_vector_type(4))) unsigned short u16x4;

__device__ __forceinline__ unsigned short f2bf(float x) {
  unsigned int u = __builtin_bit_cast(unsigned int, x);
  u += 0x7fffu + ((u >> 16) & 1u);          // RNE
  return (unsigned short)(u >> 16);
}
__device__ __forceinline__ float gelu_new(float x) {
  float u = 0.7978845608028654f * (x + 0.044715f * x * x * x);
  return x * __builtin_amdgcn_rcpf(1.0f + __expf(-2.0f * u));
}
__device__ __forceinline__ unsigned int cvtpk(float lo, float hi) {
  unsigned int r;
  asm("v_cvt_pk_bf16_f32 %0, %1, %2" : "=v"(r) : "v"(lo), "v"(hi));
  return r;
}
__device__ __forceinline__ void plswap(unsigned int& a, unsigned int& b) {
  asm("v_permlane32_swap_b32 %0, %1" : "+v"(a), "+v"(b));
}

// ---------------------------------------------------------------------------
// Weight convert+transpose: W f32 [K,N] -> Wt bf16 [N,K]
// ---------------------------------------------------------------------------
__global__ __launch_bounds__(256) void transpose_bf16(
    const float* __restrict__ W, unsigned short* __restrict__ Wt, int K, int N) {
  __shared__ float tile[32][33];
  const int n0 = blockIdx.x * 32, k0 = blockIdx.y * 32;
  const int tx = threadIdx.x, ty = threadIdx.y;
#pragma unroll
  for (int j = 0; j < 32; j += 8)
    tile[ty + j][tx] = W[(size_t)(k0 + ty + j) * N + n0 + tx];
  __syncthreads();
#pragma unroll
  for (int j = 0; j < 32; j += 8)
    Wt[(size_t)(n0 + ty + j) * K + k0 + tx] = f2bf(tile[tx][ty + j]);
}

// ---------------------------------------------------------------------------
// LayerNorm over E=1024: one block per row.
// ---------------------------------------------------------------------------
__device__ __forceinline__ void ln_core(
    f32x4 v, const float* g, const float* bb, int row, int t,
    int outf32, void* outp) {
  float s = v.x + v.y + v.z + v.w;
  float sq = v.x * v.x + v.y * v.y + v.z * v.z + v.w * v.w;
#pragma unroll
  for (int off = 32; off; off >>= 1) {
    s += __shfl_xor(s, off, 64);
    sq += __shfl_xor(sq, off, 64);
  }
  __shared__ float red[8];
  if ((t & 63) == 0) { red[t >> 6] = s; red[4 + (t >> 6)] = sq; }
  __syncthreads();
  s = red[0] + red[1] + red[2] + red[3];
  sq = red[4] + red[5] + red[6] + red[7];
  const float mean = s * (1.0f / 1024.0f);
  const float var = sq * (1.0f / 1024.0f) - mean * mean;
  const float rs = rsqrtf(var + 1e-5f);
  const f32x4 gv = ((const f32x4*)g)[t];
  const f32x4 bv = ((const f32x4*)bb)[t];
  float y0 = (v.x - mean) * rs * gv.x + bv.x;
  float y1 = (v.y - mean) * rs * gv.y + bv.y;
  float y2 = (v.z - mean) * rs * gv.z + bv.z;
  float y3 = (v.w - mean) * rs * gv.w + bv.w;
  if (outf32) {
    f32x4 o; o.x = y0; o.y = y1; o.z = y2; o.w = y3;
    ((f32x4*)outp)[(size_t)row * 256 + t] = o;
  } else {
    u16x4 pk;
    pk.x = f2bf(y0); pk.y = f2bf(y1); pk.z = f2bf(y2); pk.w = f2bf(y3);
    ((u16x4*)outp)[(size_t)row * 256 + t] = pk;
  }
}

template <int OUTF32>
__global__ __launch_bounds__(256) void ln_kernel(
    const float* __restrict__ hin, const float* __restrict__ g,
    const float* __restrict__ bb, void* __restrict__ outp) {
  const int row = blockIdx.x, t = threadIdx.x;
  const f32x4 v = ((const f32x4*)(hin + (size_t)row * 1024))[t];
  ln_core(v, g, bb, row, t, OUTF32, outp);
}

__global__ __launch_bounds__(256) void ln_wpe_kernel(
    const float* __restrict__ sent, const float* __restrict__ wpe,
    const float* __restrict__ g, const float* __restrict__ bb,
    float* __restrict__ h, unsigned short* __restrict__ xb) {
  const int row = blockIdx.x, t = threadIdx.x;
  const int s = row & 255;
  f32x4 a = ((const f32x4*)(sent + (size_t)row * 1024))[t];
  f32x4 w = ((const f32x4*)(wpe + (size_t)s * 1024))[t];
  f32x4 v = a + w;
  ((f32x4*)(h + (size_t)row * 1024))[t] = v;
  ln_core(v, g, bb, row, t, 0, xb);
}

// ---------------------------------------------------------------------------
// gemm4p: 256x256 tile, BK=64, 8 waves (2m x 4n), kk-split 4-phase schedule
// (m201-faithful): phase = (kk, m-half), each phase {ds-reads | stage |
// s_barrier | setprio 16xMFMA | s_barrier}, counted vmcnt(4)@ph0-end /
// vmcnt(2)@ph3-end only. XOR chunk^row LDS swizzle (0 conflicts, verified),
// XCD-chunk + 4-wide-stripe block swizzle, coalesced repack epilogue.
// EPI: 0 = bf16 (+bias), 1 = bf16 gelu(+bias), 2 = f32 residual +=
// Requires: M%256==0, N%256==0, K%64==0, nt>=2, (gx*gy)%8==0, gx%4==0.
// ---------------------------------------------------------------------------
template <int EPI>
__global__ __launch_bounds__(512, 2) void gemm4p(
    const unsigned short* __restrict__ A, const unsigned short* __restrict__ Bt,
    const float* __restrict__ bias, unsigned short* __restrict__ Cb,
    float* __restrict__ Hres, int N, int K, int gx, int gy) {
  constexpr int A_E = 16384;               // 256x64 A elems
  constexpr int BUF_E = A_E + 16384;       // + B 256x64
  __shared__ alignas(16) unsigned short smem[2 * BUF_E];

  const int nwg = gx * gy;
  const int dd = blockIdx.x;
  const int wrk = (dd & 7) * (nwg >> 3) + (dd >> 3);
  const int stripe = gy * 4;
  const int cg = wrk / stripe;
  const int rem = wrk - cg * stripe;
  const int by = rem >> 2;
  const int bx = cg * 4 + (rem & 3);
  const int row0 = by * 256, col0 = bx * 256;

  const int t = threadIdx.x;
  const int wid = t >> 6, l = t & 63;
  const int wm = wid >> 2, wn = wid & 3;
  const int fr = l & 15, q4 = l >> 4;

  const int cx0 = (q4 ^ (fr & 7)) * 8;          // kk0 chunk
  const int cx1 = ((4 + q4) ^ (fr & 7)) * 8;    // kk1 chunk
  const int b_r0 = (wn * 64 + fr) * 64;
  auto a_slot = [&](int m) -> int { return (wm * 128 + m * 16 + fr) * 64; };

  const int lrow = l >> 3;
  const int scol = ((l & 7) ^ (lrow & 7)) * 8;

  auto stB = [&](int tt, int win) {
    const unsigned short* s =
        Bt + (size_t)(col0 + win * 8 + lrow) * K + tt * 64 + scol;
    __builtin_amdgcn_global_load_lds(
        (const __attribute__((address_space(1))) void*)s,
        (__attribute__((address_space(3))) void*)(smem + (tt & 1) * BUF_E + A_E + win * 512),
        16, 0, 0);
  };
  auto stA = [&](int tt, int win) {
    const unsigned short* s =
        A + (size_t)(row0 + win * 8 + lrow) * K + tt * 64 + scol;
    __builtin_amdgcn_global_load_lds(
        (const __attribute__((address_space(1))) void*)s,
        (__attribute__((address_space(3))) void*)(smem + (tt & 1) * BUF_E + win * 512),
        16, 0, 0);
  };
  auto stageB_set = [&](int tt) {   // 4 loads/thread: all 256 B rows
    stB(tt, 2 * wid); stB(tt, 2 * wid + 1);
    stB(tt, 16 + 2 * wid); stB(tt, 16 + 2 * wid + 1);
  };
  auto stageA_set = [&](int tt) {   // 4 loads: A-early pair then A-late pair
    const int i0 = 2 * wid, i1 = 2 * wid + 1;
    stA(tt, i0 < 8 ? i0 : 8 + i0);       // early: rows m0-3 both wm
    stA(tt, i1 < 8 ? i1 : 8 + i1);
    stA(tt, i0 < 8 ? 8 + i0 : 16 + i0);  // late: rows m4-7
    stA(tt, i1 < 8 ? 8 + i1 : 16 + i1);
  };

  const int nt = K >> 6;

  // prologue: tile 0; leave A-late (2 newest) in flight
  stageB_set(0);
  stageA_set(0);
  asm volatile("s_waitcnt vmcnt(2)" ::: "memory");
  __builtin_amdgcn_s_barrier();
  asm volatile("" ::: "memory");

  f32x4 acc[8][4];
#pragma unroll
  for (int m = 0; m < 8; ++m)
#pragma unroll
    for (int n = 0; n < 4; ++n) {
      acc[m][n].x = 0.f; acc[m][n].y = 0.f; acc[m][n].z = 0.f; acc[m][n].w = 0.f;
    }

  for (int tc = 0; tc < nt; ++tc) {
    const unsigned short* Ab = smem + (tc & 1) * BUF_E;
    const unsigned short* Bb = Ab + A_E;
    const bool pf = (tc + 1) < nt;
    bf16x8 bfr[4], af[4];

    // ---- phase 0: kk0, B-all + A m0-3 ----
#pragma unroll
    for (int n = 0; n < 4; ++n) bfr[n] = *(const bf16x8*)(Bb + b_r0 + n * 1024 + cx0);
#pragma unroll
    for (int m = 0; m < 4; ++m) af[m] = *(const bf16x8*)(Ab + a_slot(m) + cx0);
    if (pf) stageB_set(tc + 1);
    __builtin_amdgcn_s_barrier();
    asm volatile("" ::: "memory");
    __builtin_amdgcn_s_setprio(1);
#pragma unroll
    for (int m = 0; m < 4; ++m)
#pragma unroll
      for (int n = 0; n < 4; ++n)
        acc[m][n] = __builtin_amdgcn_mfma_f32_16x16x32_bf16(af[m], bfr[n], acc[m][n], 0, 0, 0);
    __builtin_amdgcn_s_setprio(0);
    if (pf) asm volatile("s_waitcnt vmcnt(4)" ::: "memory");  // A-late(tc) landed
    else    asm volatile("s_waitcnt vmcnt(0)" ::: "memory");
    __builtin_amdgcn_s_barrier();
    asm volatile("" ::: "memory");

    // ---- phase 1: kk0, A m4-7 ----
#pragma unroll
    for (int m = 0; m < 4; ++m) af[m] = *(const bf16x8*)(Ab + a_slot(4 + m) + cx0);
    if (pf) stageA_set(tc + 1);
    __builtin_amdgcn_s_barrier();
    asm volatile("" ::: "memory");
    __builtin_amdgcn_s_setprio(1);
#pragma unroll
    for (int m = 0; m < 4; ++m)
#pragma unroll
      for (int n = 0; n < 4; ++n)
        acc[4 + m][n] = __builtin_amdgcn_mfma_f32_16x16x32_bf16(af[m], bfr[n], acc[4 + m][n], 0, 0, 0);
    __builtin_amdgcn_s_setprio(0);
    __builtin_amdgcn_s_barrier();
    asm volatile("" ::: "memory");

    // ---- phase 2: kk1, B-all + A m0-3 ----
#pragma unroll
    for (int n = 0; n < 4; ++n) bfr[n] = *(const bf16x8*)(Bb + b_r0 + n * 1024 + cx1);
#pragma unroll
    for (int m = 0; m < 4; ++m) af[m] = *(const bf16x8*)(Ab + a_slot(m) + cx1);
    __builtin_amdgcn_s_barrier();
    asm volatile("" ::: "memory");
    __builtin_amdgcn_s_setprio(1);
#pragma unroll
    for (int m = 0; m < 4; ++m)
#pragma unroll
      for (int n = 0; n < 4; ++n)
        acc[m][n] = __builtin_amdgcn_mfma_f32_16x16x32_bf16(af[m], bfr[n], acc[m][n], 0, 0, 0);
    __builtin_amdgcn_s_setprio(0);
    __builtin_amdgcn_s_barrier();
    asm volatile("" ::: "memory");

    // ---- phase 3: kk1, A m4-7 ----
#pragma unroll
    for (int m = 0; m < 4; ++m) af[m] = *(const bf16x8*)(Ab + a_slot(4 + m) + cx1);
    __builtin_amdgcn_s_barrier();
    asm volatile("" ::: "memory");
    __builtin_amdgcn_s_setprio(1);
#pragma unroll
    for (int m = 0; m < 4; ++m)
#pragma unroll
      for (int n = 0; n < 4; ++n)
        acc[4 + m][n] = __builtin_amdgcn_mfma_f32_16x16x32_bf16(af[m], bfr[n], acc[4 + m][n], 0, 0, 0);
    __builtin_amdgcn_s_setprio(0);
    if (pf) asm volatile("s_waitcnt vmcnt(2)" ::: "memory");  // B+A-early(tc+1) landed
    else    asm volatile("s_waitcnt vmcnt(0)" ::: "memory");
    __builtin_amdgcn_s_barrier();
    asm volatile("" ::: "memory");
  }

  // ---- epilogue ----
  if constexpr (EPI == 2) {
#pragma unroll
    for (int n = 0; n < 4; ++n) {
      const int col = col0 + wn * 64 + n * 16 + fr;
      const float bi = bias[col];
#pragma unroll
      for (int m = 0; m < 8; ++m)
#pragma unroll
        for (int e = 0; e < 4; ++e) {
          const int row = row0 + wm * 128 + m * 16 + q4 * 4 + e;
          Hres[(size_t)row * N + col] += acc[m][n][e] + bi;
        }
    }
  } else {
    char* wreg = (char*)smem + wid * 9216;   // 64 rows x 144 B per wave
    float bi[4];
#pragma unroll
    for (int n = 0; n < 4; ++n) bi[n] = bias[col0 + wn * 64 + n * 16 + fr];
#pragma unroll
    for (int half = 0; half < 2; ++half) {
#pragma unroll
      for (int m = 0; m < 4; ++m)
#pragma unroll
        for (int n = 0; n < 4; ++n)
#pragma unroll
          for (int e = 0; e < 4; ++e) {
            float v = acc[half * 4 + m][n][e] + bi[n];
            if (EPI == 1) v = gelu_new(v);
            *(unsigned short*)(wreg + (m * 16 + q4 * 4 + e) * 144 +
                               (n * 16 + fr) * 2) = f2bf(v);
          }
#pragma unroll
      for (int rb = 0; rb < 8; ++rb) {
        const int rowl = rb * 8 + (l >> 3);
        u16x8 vv = *(const u16x8*)(wreg + rowl * 144 + (l & 7) * 16);
        const int rg = row0 + wm * 128 + half * 64 + rowl;
        *(u16x8*)(Cb + (size_t)rg * N + col0 + wn * 64 + (l & 7) * 8) = vv;
      }
    }
  }
}

// ---------------------------------------------------------------------------
// gemm8p<128,2>: round-6 2-phase BM=128 kernel (fallback mlp-proj only).
// ---------------------------------------------------------------------------
template <int BM, int EPI>
__global__ __launch_bounds__(512, 2) void gemm8p(
    const unsigned short* __restrict__ A, const unsigned short* __restrict__ Bt,
    const float* __restrict__ bias, unsigned short* __restrict__ Cb,
    float* __restrict__ Hres, int N, int K, int gx, int gy) {
  constexpr int M_REP = BM / 32;
  constexpr int MH = M_REP / 2;
  constexpr int A_E = BM * 64;
  constexpr int BUF_E = A_E + 16384;
  __shared__ alignas(16) unsigned short smem[2 * BUF_E];

  const int nwg = gx * gy;
  const int dd = blockIdx.x;
  const int wrk = (dd & 7) * (nwg >> 3) + (dd >> 3);
  const int stripe = gy * 4;
  const int cg = wrk / stripe;
  const int rem = wrk - cg * stripe;
  const int by = rem >> 2;
  const int bx = cg * 4 + (rem & 3);
  const int row0 = by * BM, col0 = bx * 256;

  const int t = threadIdx.x;
  const int wid = t >> 6, l = t & 63;
  const int wm = wid >> 2, wn = wid & 3;
  const int fr = l & 15, q4 = l >> 4;

  const int cx0 = (q4 ^ (fr & 7)) * 8;
  const int cx1 = ((4 + q4) ^ (fr & 7)) * 8;
  const int b_r0 = (wn * 64 + fr) * 64;
  auto a_slot = [&](int m) -> int {
    if constexpr (BM == 256) return (wm * 128 + m * 16 + fr) * 64;
    else return ((m >> 1) * 64 + wm * 32 + (m & 1) * 16 + fr) * 64;
  };

  const int lrow = l >> 3;
  const int scol = ((l & 7) ^ (lrow & 7)) * 8;

  auto stB = [&](int tt, int win) {
    const unsigned short* s =
        Bt + (size_t)(col0 + win * 8 + lrow) * K + tt * 64 + scol;
    __builtin_amdgcn_global_load_lds(
        (const __attribute__((address_space(1))) void*)s,
        (__attribute__((address_space(3))) void*)(smem + (tt & 1) * BUF_E + A_E + win * 512),
        16, 0, 0);
  };
  auto stA = [&](int tt, int win) {
    int rb;
    if constexpr (BM == 256) rb = win * 8;
    else rb = ((win >> 2) & 1) * 64 + (win >> 3) * 32 + (win & 3) * 8;
    const unsigned short* s =
        A + (size_t)(row0 + rb + lrow) * K + tt * 64 + scol;
    __builtin_amdgcn_global_load_lds(
        (const __attribute__((address_space(1))) void*)s,
        (__attribute__((address_space(3))) void*)(smem + (tt & 1) * BUF_E + win * 512),
        16, 0, 0);
  };
  auto stageB_set = [&](int tt) {
    stB(tt, 2 * wid); stB(tt, 2 * wid + 1);
    stB(tt, 16 + 2 * wid); stB(tt, 16 + 2 * wid + 1);
  };
  auto stageA_set = [&](int tt) {
    if constexpr (BM == 256) {
      const int i0 = 2 * wid, i1 = 2 * wid + 1;
      stA(tt, i0 < 8 ? i0 : 8 + i0);
      stA(tt, i1 < 8 ? i1 : 8 + i1);
      stA(tt, i0 < 8 ? 8 + i0 : 16 + i0);
      stA(tt, i1 < 8 ? 8 + i1 : 16 + i1);
    } else {
      stA(tt, wid);
      stA(tt, 8 + wid);
    }
  };
  constexpr int VM_BOUND = (BM == 256) ? 2 : 1;

  const int nt = K >> 6;

  stageB_set(0);
  stageA_set(0);
  asm volatile("s_waitcnt vmcnt(%0)" :: "i"(VM_BOUND) : "memory");
  __builtin_amdgcn_s_barrier();
  asm volatile("" ::: "memory");

  f32x4 acc[M_REP][4];
#pragma unroll
  for (int m = 0; m < M_REP; ++m)
#pragma unroll
    for (int n = 0; n < 4; ++n) {
      acc[m][n].x = 0.f; acc[m][n].y = 0.f; acc[m][n].z = 0.f; acc[m][n].w = 0.f;
    }

  for (int tc = 0; tc < nt; ++tc) {
    const unsigned short* Ab = smem + (tc & 1) * BUF_E;
    const unsigned short* Bb = Ab + A_E;
    const bool pf = (tc + 1) < nt;

    bf16x8 bfr[4][2], af[MH][2];
#pragma unroll
    for (int n = 0; n < 4; ++n) {
      bfr[n][0] = *(const bf16x8*)(Bb + b_r0 + n * 1024 + cx0);
      bfr[n][1] = *(const bf16x8*)(Bb + b_r0 + n * 1024 + cx1);
    }
#pragma unroll
    for (int m = 0; m < MH; ++m) {
      af[m][0] = *(const bf16x8*)(Ab + a_slot(m) + cx0);
      af[m][1] = *(const bf16x8*)(Ab + a_slot(m) + cx1);
    }
    if (pf) stageB_set(tc + 1);
    __builtin_amdgcn_s_setprio(1);
#pragma unroll
    for (int m = 0; m < MH; ++m)
#pragma unroll
      for (int n = 0; n < 4; ++n) {
        acc[m][n] = __builtin_amdgcn_mfma_f32_16x16x32_bf16(
            af[m][0], bfr[n][0], acc[m][n], 0, 0, 0);
        acc[m][n] = __builtin_amdgcn_mfma_f32_16x16x32_bf16(
            af[m][1], bfr[n][1], acc[m][n], 0, 0, 0);
      }
    __builtin_amdgcn_s_setprio(0);
    if (pf) asm volatile("s_waitcnt vmcnt(4)" ::: "memory");
    else    asm volatile("s_waitcnt vmcnt(0)" ::: "memory");
    __builtin_amdgcn_s_barrier();
    asm volatile("" ::: "memory");

    bf16x8 ah[MH][2];
#pragma unroll
    for (int m = 0; m < MH; ++m) {
      ah[m][0] = *(const bf16x8*)(Ab + a_slot(MH + m) + cx0);
      ah[m][1] = *(const bf16x8*)(Ab + a_slot(MH + m) + cx1);
    }
    if (pf) stageA_set(tc + 1);
    __builtin_amdgcn_s_setprio(1);
#pragma unroll
    for (int m = 0; m < MH; ++m)
#pragma unroll
      for (int n = 0; n < 4; ++n) {
        acc[MH + m][n] = __builtin_amdgcn_mfma_f32_16x16x32_bf16(
            ah[m][0], bfr[n][0], acc[MH + m][n], 0, 0, 0);
        acc[MH + m][n] = __builtin_amdgcn_mfma_f32_16x16x32_bf16(
            ah[m][1], bfr[n][1], acc[MH + m][n], 0, 0, 0);
      }
    __builtin_amdgcn_s_setprio(0);
    if (pf) asm volatile("s_waitcnt vmcnt(%0)" :: "i"(VM_BOUND) : "memory");
    else    asm volatile("s_waitcnt vmcnt(0)" ::: "memory");
    __builtin_amdgcn_s_barrier();
    asm volatile("" ::: "memory");
  }

  if constexpr (EPI == 2) {
#pragma unroll
    for (int n = 0; n < 4; ++n) {
      const int col = col0 + wn * 64 + n * 16 + fr;
      const float bi = bias[col];
#pragma unroll
      for (int m = 0; m < M_REP; ++m)
#pragma unroll
        for (int e = 0; e < 4; ++e) {
          const int row = row0 + wm * (BM / 2) + m * 16 + q4 * 4 + e;
          Hres[(size_t)row * N + col] += acc[m][n][e] + bi;
        }
    }
  } else {
    char* wreg = (char*)smem + wid * 9216;
    float bi[4];
#pragma unroll
    for (int n = 0; n < 4; ++n) bi[n] = bias[col0 + wn * 64 + n * 16 + fr];
#pragma unroll
    for (int half = 0; half < M_REP / 4; ++half) {
#pragma unroll
      for (int m = 0; m < 4; ++m)
#pragma unroll
        for (int n = 0; n < 4; ++n)
#pragma unroll
          for (int e = 0; e < 4; ++e) {
            float v = acc[half * 4 + m][n][e] + bi[n];
            if (EPI == 1) v = gelu_new(v);
            *(unsigned short*)(wreg + (m * 16 + q4 * 4 + e) * 144 +
                               (n * 16 + fr) * 2) = f2bf(v);
          }
#pragma unroll
      for (int rb = 0; rb < 8; ++rb) {
        const int rowl = rb * 8 + (l >> 3);
        u16x8 vv = *(const u16x8*)(wreg + rowl * 144 + (l & 7) * 16);
        const int rg = row0 + wm * (BM / 2) + half * 64 + rowl;
        *(u16x8*)(Cb + (size_t)rg * N + col0 + wn * 64 + (l & 7) * 8) = vv;
      }
    }
  }
}

// ---------------------------------------------------------------------------
// MFMA flash attention (unchanged; verified rounds 3-6).
// ---------------------------------------------------------------------------
__global__ __launch_bounds__(256) void attn_mfma(
    const unsigned short* __restrict__ qkv, unsigned short* __restrict__ aout,
    int b0) {
  __shared__ alignas(16) unsigned short Klds[256 * 64];
  __shared__ alignas(16) unsigned short Vt[64 * 256];
  const int bh = blockIdx.x;
  const int bl = bh >> 4, hd = bh & 15;
  const size_t base = (size_t)bl * 256 * 3072 + (size_t)hd * 64;
  const int t = threadIdx.x;
  const int w = t >> 6, l = t & 63;
  const int lq = l & 31, hl = l >> 5;

#pragma unroll
  for (int i = 0; i < 8; ++i) {
    const int r = i * 32 + (t >> 3);
    const int c = t & 7;
    u16x8 kv = *(const u16x8*)(qkv + base + (size_t)r * 3072 + 1024 + c * 8);
    *(u16x8*)(Klds + r * 64 + ((c ^ (r & 7)) * 8)) = kv;
    u16x8 vv = *(const u16x8*)(qkv + base + (size_t)r * 3072 + 2048 + c * 8);
#pragma unroll
    for (int j = 0; j < 8; ++j) {
      const int d = c * 8 + j;
      Vt[d * 256 + (((r >> 3) ^ (d & 31)) * 8) + (r & 7)] = vv[j];
    }
  }

  const int q0 = w * 64;
  bf16x8 qf[2][4];
#pragma unroll
  for (int n = 0; n < 2; ++n)
#pragma unroll
    for (int d16 = 0; d16 < 4; ++d16)
      qf[n][d16] = *(const bf16x8*)(qkv + base +
          (size_t)(q0 + n * 32 + lq) * 3072 + d16 * 16 + hl * 8);
  __syncthreads();

  const float cs = 0.125f * 1.44269504088896f;
  f32x16 O[2][2];
#pragma unroll
  for (int m = 0; m < 2; ++m)
#pragma unroll
    for (int n = 0; n < 2; ++n)
#pragma unroll
      for (int e = 0; e < 16; ++e) O[m][n][e] = 0.f;
  float mrun[2] = {-3.0e38f, -3.0e38f};
  float lrun[2] = {0.f, 0.f};

  const int ktmax = (q0 + 63) >> 5;
  for (int kt = 0; kt <= ktmax; ++kt) {
    bf16x8 kf[4];
    const int krow = kt * 32 + lq;
#pragma unroll
    for (int d16 = 0; d16 < 4; ++d16) {
      const int chunk = (d16 * 2 + hl) ^ (krow & 7);
      kf[d16] = *(const bf16x8*)(Klds + krow * 64 + chunk * 8);
    }
    const int nlo = (kt * 32 > q0 + 31) ? 1 : 0;
    bf16x8 pfrag[2][2];
#pragma unroll
    for (int n = 0; n < 2; ++n) {
      if (n < nlo) continue;
      f32x16 s;
#pragma unroll
      for (int e = 0; e < 16; ++e) s[e] = 0.f;
#pragma unroll
      for (int d16 = 0; d16 < 4; ++d16)
        s = __builtin_amdgcn_mfma_f32_32x32x16_bf16(kf[d16], qf[n][d16], s, 0, 0, 0);
      const int qg = q0 + n * 32 + lq;
      float sv[16];
#pragma unroll
      for (int r = 0; r < 16; ++r) {
        const int kg = kt * 32 + (r & 3) + 8 * (r >> 2) + 4 * hl;
        const float x = s[r] * cs;
        sv[r] = (kg > qg) ? -3.0e38f : x;
      }
      float pmax = sv[0];
#pragma unroll
      for (int r = 1; r < 16; ++r) pmax = fmaxf(pmax, sv[r]);
      pmax = fmaxf(pmax, __shfl_xor(pmax, 32, 64));
      const float nm = fmaxf(mrun[n], pmax);
      const float alpha = exp2f(mrun[n] - nm);
      mrun[n] = nm;
      float psum = 0.f;
#pragma unroll
      for (int r = 0; r < 16; ++r) {
        sv[r] = exp2f(sv[r] - nm);
        psum += sv[r];
      }
      psum += __shfl_xor(psum, 32, 64);
      lrun[n] = lrun[n] * alpha + psum;
#pragma unroll
      for (int m = 0; m < 2; ++m)
#pragma unroll
        for (int e = 0; e < 16; ++e) O[m][n][e] *= alpha;
#pragma unroll
      for (int h = 0; h < 2; ++h) {
        unsigned int a0 = cvtpk(sv[h * 8 + 0], sv[h * 8 + 1]);
        unsigned int a1 = cvtpk(sv[h * 8 + 2], sv[h * 8 + 3]);
        unsigned int c0 = cvtpk(sv[h * 8 + 4], sv[h * 8 + 5]);
        unsigned int c1 = cvtpk(sv[h * 8 + 6], sv[h * 8 + 7]);
        plswap(a0, c0);
        plswap(a1, c1);
        u32x4 fw; fw.x = a0; fw.y = a1; fw.z = c0; fw.w = c1;
        pfrag[n][h] = __builtin_bit_cast(bf16x8, fw);
      }
    }
#pragma unroll
    for (int m = 0; m < 2; ++m)
#pragma unroll
      for (int h = 0; h < 2; ++h) {
        const int dd = m * 32 + lq;
        const int chunk = (kt * 4 + h * 2 + hl) ^ (dd & 31);
        bf16x8 vf = *(const bf16x8*)(Vt + dd * 256 + chunk * 8);
#pragma unroll
        for (int n = 0; n < 2; ++n)
          if (n >= nlo)
            O[m][n] = __builtin_amdgcn_mfma_f32_32x32x16_bf16(vf, pfrag[n][h], O[m][n], 0, 0, 0);
      }
  }

#pragma unroll
  for (int n = 0; n < 2; ++n) {
    const float inv = 1.0f / lrun[n];
    const size_t row = (size_t)(b0 + bl) * 256 + q0 + n * 32 + lq;
#pragma unroll
    for (int m = 0; m < 2; ++m) {
#pragma unroll
      for (int qd = 0; qd < 4; ++qd) {
        u16x4 pk;
#pragma unroll
        for (int e = 0; e < 4; ++e) pk[e] = f2bf(O[m][n][qd * 4 + e] * inv);
        *(u16x4*)(aout + row * 1024 + hd * 64 + m * 32 + qd * 8 + hl * 4) = pk;
      }
    }
  }
}

// ---------------------------------------------------------------------------
// Loss
// ---------------------------------------------------------------------------
__device__ __forceinline__ float block_reduce_sum256(float v) {
#pragma unroll
  for (int off = 32; off; off >>= 1) v += __shfl_xor(v, off, 64);
  __shared__ float red[4];
  const int t = threadIdx.x;
  if ((t & 63) == 0) red[t >> 6] = v;
  __syncthreads();
  return red[0] + red[1] + red[2] + red[3];
}

__global__ __launch_bounds__(256) void loss_partial(
    const float* __restrict__ hf, const float* __restrict__ sent,
    float* __restrict__ part) {
  const int s = blockIdx.x, t = threadIdx.x;
  f32x4 a = ((const f32x4*)(hf + (size_t)s * 1024))[t];
  f32x4 b = ((const f32x4*)(sent + (size_t)(s + 1) * 1024))[t];
  f32x4 d = a - b;
  float v = d.x * d.x + d.y * d.y + d.z * d.z + d.w * d.w;
  float tot = block_reduce_sum256(v);
  if (t == 0) part[s] = tot;
}

__global__ __launch_bounds__(256) void loss_final(
    const float* __restrict__ part, float* __restrict__ out) {
  const int t = threadIdx.x;
  float v = (t < 255) ? part[t] : 0.f;
  float s = block_reduce_sum256(v);
  if (t == 0) out[0] = s * (1.0f / (255.0f * 1024.0f));
}

// ---------------------------------------------------------------------------
// Workspace layouts
// Chunked (fallback, ~120 MiB) and Full-M (~184 MiB, used if ws_size allows)
// ---------------------------------------------------------------------------
constexpr size_t C_X     = 0;
constexpr size_t C_QKV   = 33554432;
constexpr size_t C_WQKV  = C_QKV + 67108864;
constexpr size_t C_WPROJ = C_WQKV + 6291456;
constexpr size_t C_WFC   = C_WPROJ + 2097152;
constexpr size_t C_WMLP  = C_WFC + 8388608;
constexpr size_t C_PART  = C_WMLP + 8388608;

constexpr size_t F_X     = 0;                      // 32 MiB
constexpr size_t F_U     = 33554432;               // union qkv 96 / m 128 MiB
constexpr size_t F_WQKV  = F_U + 134217728;
constexpr size_t F_WPROJ = F_WQKV + 6291456;
constexpr size_t F_WFC   = F_WPROJ + 2097152;
constexpr size_t F_WMLP  = F_WFC + 8388608;
constexpr size_t F_PART  = F_WMLP + 8388608;
constexpr size_t F_NEED  = F_PART + 4096;

extern "C" void kernel_launch(void* const* d_in, const int* in_sizes, int n_in,
                              void* d_out, int out_size, void* d_ws, size_t ws_size,
                              hipStream_t stream) {
  (void)in_sizes; (void)n_in; (void)out_size;
  const float* sent    = (const float*)d_in[0];
  const float* wpe     = (const float*)d_in[1];
  const float* ln1_g   = (const float*)d_in[2];
  const float* ln1_b   = (const float*)d_in[3];
  const float* attn_w  = (const float*)d_in[4];
  const float* attn_b  = (const float*)d_in[5];
  const float* attn_pw = (const float*)d_in[6];
  const float* attn_pb = (const float*)d_in[7];
  const float* ln2_g   = (const float*)d_in[8];
  const float* ln2_b   = (const float*)d_in[9];
  const float* fc_w    = (const float*)d_in[10];
  const float* fc_b    = (const float*)d_in[11];
  const float* mlp_w   = (const float*)d_in[12];
  const float* mlp_b   = (const float*)d_in[13];
  const float* lnf_g   = (const float*)d_in[14];
  const float* lnf_b   = (const float*)d_in[15];
  float* out_h = (float*)d_out;
  float* h = out_h;

  char* ws = (char*)d_ws;
  const bool fullm = ws_size >= F_NEED;

  unsigned short* xb    = (unsigned short*)(ws + (fullm ? F_X : C_X));
  unsigned short* ub    = (unsigned short*)(ws + (fullm ? F_U : C_QKV));
  unsigned short* wqkv  = (unsigned short*)(ws + (fullm ? F_WQKV : C_WQKV));
  unsigned short* wproj = (unsigned short*)(ws + (fullm ? F_WPROJ : C_WPROJ));
  unsigned short* wfc   = (unsigned short*)(ws + (fullm ? F_WFC : C_WFC));
  unsigned short* wmlp  = (unsigned short*)(ws + (fullm ? F_WMLP : C_WMLP));
  float* part           = (float*)(ws + (fullm ? F_PART : C_PART));

  const dim3 tb(32, 8, 1);
  for (int i = 0; i < 2; ++i) {
    transpose_bf16<<<dim3(96, 32), tb, 0, stream>>>(
        attn_w + (size_t)i * 1024 * 3072, wqkv, 1024, 3072);
    transpose_bf16<<<dim3(32, 32), tb, 0, stream>>>(
        attn_pw + (size_t)i * 1024 * 1024, wproj, 1024, 1024);
    transpose_bf16<<<dim3(128, 32), tb, 0, stream>>>(
        fc_w + (size_t)i * 1024 * 4096, wfc, 1024, 4096);
    transpose_bf16<<<dim3(32, 128), tb, 0, stream>>>(
        mlp_w + (size_t)i * 4096 * 1024, wmlp, 4096, 1024);

    // --- attention block ---
    if (i == 0)
      ln_wpe_kernel<<<16384, 256, 0, stream>>>(sent, wpe, ln1_g, ln1_b, h, xb);
    else
      ln_kernel<0><<<16384, 256, 0, stream>>>(h, ln1_g + i * 1024, ln1_b + i * 1024, xb);

    if (fullm) {
      gemm4p<0><<<768, 512, 0, stream>>>(
          xb, wqkv, attn_b + i * 3072, ub, nullptr, 3072, 1024, 12, 64);
      attn_mfma<<<1024, 256, 0, stream>>>(ub, xb, 0);
    } else {
      for (int c = 0; c < 2; ++c) {
        const size_t r0 = (size_t)c * 8192;
        gemm4p<0><<<384, 512, 0, stream>>>(
            xb + r0 * 1024, wqkv, attn_b + i * 3072, ub, nullptr, 3072, 1024, 12, 32);
        attn_mfma<<<512, 256, 0, stream>>>(ub, xb, c * 32);
      }
    }
    gemm4p<2><<<256, 512, 0, stream>>>(
        xb, wproj, attn_pb + i * 1024, nullptr, h, 1024, 1024, 4, 64);

    // --- MLP block ---
    ln_kernel<0><<<16384, 256, 0, stream>>>(h, ln2_g + i * 1024, ln2_b + i * 1024, xb);
    if (fullm) {
      gemm4p<1><<<1024, 512, 0, stream>>>(
          xb, wfc, fc_b + i * 4096, ub, nullptr, 4096, 1024, 16, 64);
      gemm4p<2><<<256, 512, 0, stream>>>(
          ub, wmlp, mlp_b + i * 1024, nullptr, h, 1024, 4096, 4, 64);
    } else {
      for (int c = 0; c < 2; ++c) {
        const size_t r0 = (size_t)c * 8192;
        gemm4p<1><<<512, 512, 0, stream>>>(
            xb + r0 * 1024, wfc, fc_b + i * 4096, ub, nullptr, 4096, 1024, 16, 32);
        gemm8p<128, 2><<<256, 512, 0, stream>>>(
            ub, wmlp, mlp_b + i * 1024, nullptr, h + r0 * 1024, 1024, 4096, 4, 64);
      }
    }
  }

  ln_kernel<1><<<16384, 256, 0, stream>>>(h, lnf_g, lnf_b, out_h);
  loss_partial<<<255, 256, 0, stream>>>(out_h, sent, part);
  loss_final<<<1, 256, 0, stream>>>(part, out_h + 16777216);
}

// Round 8
// 1138.027 us; speedup vs baseline: 2.5045x; 1.0449x over previous
//
#include <hip/hip_runtime.h>
#include <cstdint>
#include <cstddef>

// ---------------------------------------------------------------------------
// Model dims (fixed): B=64 S=256 E=1024 H=16 D=64 NL=2 FF=4096; T=16384 rows.
// h (residual stream, f32) lives in d_out.
// ---------------------------------------------------------------------------

typedef __attribute__((ext_vector_type(4))) float f32x4;
typedef __attribute__((ext_vector_type(16))) float f32x16;
typedef __attribute__((ext_vector_type(8))) __bf16 bf16x8;
typedef __attribute__((ext_vector_type(4))) unsigned int u32x4;
typedef __attribute__((ext_vector_type(8))) unsigned short u16x8;
typedef __attribute__((ext_vector_type(4))) unsigned short u16x4;

__device__ __forceinline__ unsigned short f2bf(float x) {
  unsigned int u = __builtin_bit_cast(unsigned int, x);
  u += 0x7fffu + ((u >> 16) & 1u);          // RNE
  return (unsigned short)(u >> 16);
}
__device__ __forceinline__ float gelu_new(float x) {
  float u = 0.7978845608028654f * (x + 0.044715f * x * x * x);
  return x * __builtin_amdgcn_rcpf(1.0f + __expf(-2.0f * u));
}
__device__ __forceinline__ unsigned int cvtpk(float lo, float hi) {
  unsigned int r;
  asm("v_cvt_pk_bf16_f32 %0, %1, %2" : "=v"(r) : "v"(lo), "v"(hi));
  return r;
}
__device__ __forceinline__ void plswap(unsigned int& a, unsigned int& b) {
  asm("v_permlane32_swap_b32 %0, %1" : "+v"(a), "+v"(b));
}

// ---------------------------------------------------------------------------
// Weight convert+transpose: W f32 [K,N] -> Wt bf16 [N,K]
// ---------------------------------------------------------------------------
__global__ __launch_bounds__(256) void transpose_bf16(
    const float* __restrict__ W, unsigned short* __restrict__ Wt, int K, int N) {
  __shared__ float tile[32][33];
  const int n0 = blockIdx.x * 32, k0 = blockIdx.y * 32;
  const int tx = threadIdx.x, ty = threadIdx.y;
#pragma unroll
  for (int j = 0; j < 32; j += 8)
    tile[ty + j][tx] = W[(size_t)(k0 + ty + j) * N + n0 + tx];
  __syncthreads();
#pragma unroll
  for (int j = 0; j < 32; j += 8)
    Wt[(size_t)(n0 + ty + j) * K + k0 + tx] = f2bf(tile[tx][ty + j]);
}

// ---------------------------------------------------------------------------
// LayerNorm over E=1024: one block per row.
// ---------------------------------------------------------------------------
__device__ __forceinline__ void ln_core(
    f32x4 v, const float* g, const float* bb, int row, int t,
    int outf32, void* outp) {
  float s = v.x + v.y + v.z + v.w;
  float sq = v.x * v.x + v.y * v.y + v.z * v.z + v.w * v.w;
#pragma unroll
  for (int off = 32; off; off >>= 1) {
    s += __shfl_xor(s, off, 64);
    sq += __shfl_xor(sq, off, 64);
  }
  __shared__ float red[8];
  if ((t & 63) == 0) { red[t >> 6] = s; red[4 + (t >> 6)] = sq; }
  __syncthreads();
  s = red[0] + red[1] + red[2] + red[3];
  sq = red[4] + red[5] + red[6] + red[7];
  const float mean = s * (1.0f / 1024.0f);
  const float var = sq * (1.0f / 1024.0f) - mean * mean;
  const float rs = rsqrtf(var + 1e-5f);
  const f32x4 gv = ((const f32x4*)g)[t];
  const f32x4 bv = ((const f32x4*)bb)[t];
  float y0 = (v.x - mean) * rs * gv.x + bv.x;
  float y1 = (v.y - mean) * rs * gv.y + bv.y;
  float y2 = (v.z - mean) * rs * gv.z + bv.z;
  float y3 = (v.w - mean) * rs * gv.w + bv.w;
  if (outf32) {
    f32x4 o; o.x = y0; o.y = y1; o.z = y2; o.w = y3;
    ((f32x4*)outp)[(size_t)row * 256 + t] = o;
  } else {
    u16x4 pk;
    pk.x = f2bf(y0); pk.y = f2bf(y1); pk.z = f2bf(y2); pk.w = f2bf(y3);
    ((u16x4*)outp)[(size_t)row * 256 + t] = pk;
  }
}

template <int OUTF32>
__global__ __launch_bounds__(256) void ln_kernel(
    const float* __restrict__ hin, const float* __restrict__ g,
    const float* __restrict__ bb, void* __restrict__ outp) {
  const int row = blockIdx.x, t = threadIdx.x;
  const f32x4 v = ((const f32x4*)(hin + (size_t)row * 1024))[t];
  ln_core(v, g, bb, row, t, OUTF32, outp);
}

__global__ __launch_bounds__(256) void ln_wpe_kernel(
    const float* __restrict__ sent, const float* __restrict__ wpe,
    const float* __restrict__ g, const float* __restrict__ bb,
    float* __restrict__ h, unsigned short* __restrict__ xb) {
  const int row = blockIdx.x, t = threadIdx.x;
  const int s = row & 255;
  f32x4 a = ((const f32x4*)(sent + (size_t)row * 1024))[t];
  f32x4 w = ((const f32x4*)(wpe + (size_t)s * 1024))[t];
  f32x4 v = a + w;
  ((f32x4*)(h + (size_t)row * 1024))[t] = v;
  ln_core(v, g, bb, row, t, 0, xb);
}

// ---------------------------------------------------------------------------
// gemmp: 256x256 tile, BK=64, 8 waves (2m x 4n), register-pipelined schedule:
//   top:  ds_read B(kk0,kk1) + A-lo(kk0,kk1)  [16 x b128]
//         stage B(tc+1); MFMA C0 (A-lo x kk0); stage A(tc+1);
//         MFMA C1 (A-lo x kk1)
//   mid:  vmcnt(8) + s_barrier          // forces only A-late(tc); 8 in flight
//         ds_read A-hi(kk0,kk1) [8]; MFMA C2; MFMA C3
//   end:  vmcnt(2) + s_barrier          // forces B+A-early(tc+1)
// One lgkm hard-stall per cluster-pair instead of per cluster. setprio around
// clusters. XOR chunk^row LDS swizzle (0 conflicts). XCD-compact block
// rectangles: by-groups of 4, bx-sweep (A 2MB L2-resident per group).
// EPI: 0 = bf16 (+bias), 1 = bf16 gelu(+bias), 2 = f32 residual +=
// Requires: M%256==0, N%256==0, K%64==0, nt>=2, (gx*gy)%8==0, gy%4==0.
// ---------------------------------------------------------------------------
template <int EPI>
__global__ __launch_bounds__(512, 2) void gemmp(
    const unsigned short* __restrict__ A, const unsigned short* __restrict__ Bt,
    const float* __restrict__ bias, unsigned short* __restrict__ Cb,
    float* __restrict__ Hres, int N, int K, int gx, int gy) {
  constexpr int A_E = 16384;               // 256x64 A elems
  constexpr int BUF_E = A_E + 16384;       // + B 256x64
  __shared__ alignas(16) unsigned short smem[2 * BUF_E];

  // ---- block swizzle: XCD contiguous range; by-groups of 4, bx-sweep ----
  const int nwg = gx * gy;
  const int dd = blockIdx.x;
  const int wrk = (dd & 7) * (nwg >> 3) + (dd >> 3);
  const int grp = wrk / (gx * 4);
  const int r = wrk - grp * (gx * 4);
  const int bx = r >> 2;
  const int by = grp * 4 + (r & 3);
  const int row0 = by * 256, col0 = bx * 256;

  const int t = threadIdx.x;
  const int wid = t >> 6, l = t & 63;
  const int wm = wid >> 2, wn = wid & 3;
  const int fr = l & 15, q4 = l >> 4;

  const int cx0 = (q4 ^ (fr & 7)) * 8;          // kk0 chunk
  const int cx1 = ((4 + q4) ^ (fr & 7)) * 8;    // kk1 chunk
  const int b_r0 = (wn * 64 + fr) * 64;
  auto a_slot = [&](int m) -> int { return (wm * 128 + m * 16 + fr) * 64; };

  const int lrow = l >> 3;
  const int scol = ((l & 7) ^ (lrow & 7)) * 8;

  auto stB = [&](int tt, int win) {
    const unsigned short* s =
        Bt + (size_t)(col0 + win * 8 + lrow) * K + tt * 64 + scol;
    __builtin_amdgcn_global_load_lds(
        (const __attribute__((address_space(1))) void*)s,
        (__attribute__((address_space(3))) void*)(smem + (tt & 1) * BUF_E + A_E + win * 512),
        16, 0, 0);
  };
  auto stA = [&](int tt, int win) {
    const unsigned short* s =
        A + (size_t)(row0 + win * 8 + lrow) * K + tt * 64 + scol;
    __builtin_amdgcn_global_load_lds(
        (const __attribute__((address_space(1))) void*)s,
        (__attribute__((address_space(3))) void*)(smem + (tt & 1) * BUF_E + win * 512),
        16, 0, 0);
  };
  auto stageB_set = [&](int tt) {   // 4 loads/thread: all 256 B rows
    stB(tt, 2 * wid); stB(tt, 2 * wid + 1);
    stB(tt, 16 + 2 * wid); stB(tt, 16 + 2 * wid + 1);
  };
  auto stageA_set = [&](int tt) {   // early pair (A-lo rows) then late pair
    const int i0 = 2 * wid, i1 = 2 * wid + 1;
    stA(tt, i0 < 8 ? i0 : 8 + i0);       // early: rows 0-63, 128-191 (m0-3)
    stA(tt, i1 < 8 ? i1 : 8 + i1);
    stA(tt, i0 < 8 ? 8 + i0 : 16 + i0);  // late: rows 64-127, 192-255 (m4-7)
    stA(tt, i1 < 8 ? 8 + i1 : 16 + i1);
  };

  const int nt = K >> 6;

  // prologue: tile 0; leave A-late(0) (2 newest loads) in flight
  stageB_set(0);
  stageA_set(0);
  asm volatile("s_waitcnt vmcnt(2)" ::: "memory");
  __builtin_amdgcn_s_barrier();
  asm volatile("" ::: "memory");

  f32x4 acc[8][4];
#pragma unroll
  for (int m = 0; m < 8; ++m)
#pragma unroll
    for (int n = 0; n < 4; ++n) {
      acc[m][n].x = 0.f; acc[m][n].y = 0.f; acc[m][n].z = 0.f; acc[m][n].w = 0.f;
    }

  for (int tc = 0; tc < nt; ++tc) {
    const unsigned short* Ab = smem + (tc & 1) * BUF_E;
    const unsigned short* Bb = Ab + A_E;
    const bool pf = (tc + 1) < nt;

    // ---- tile-top reads: B both kk, A-lo both kk (16 x ds_read_b128) ----
    bf16x8 b0[4], b1[4], a0[4], a1[4];
#pragma unroll
    for (int n = 0; n < 4; ++n) b0[n] = *(const bf16x8*)(Bb + b_r0 + n * 1024 + cx0);
#pragma unroll
    for (int m = 0; m < 4; ++m) a0[m] = *(const bf16x8*)(Ab + a_slot(m) + cx0);
#pragma unroll
    for (int n = 0; n < 4; ++n) b1[n] = *(const bf16x8*)(Bb + b_r0 + n * 1024 + cx1);
#pragma unroll
    for (int m = 0; m < 4; ++m) a1[m] = *(const bf16x8*)(Ab + a_slot(m) + cx1);

    if (pf) stageB_set(tc + 1);

    // ---- C0: A-lo x kk0 ----
    __builtin_amdgcn_s_setprio(1);
#pragma unroll
    for (int m = 0; m < 4; ++m)
#pragma unroll
      for (int n = 0; n < 4; ++n)
        acc[m][n] = __builtin_amdgcn_mfma_f32_16x16x32_bf16(a0[m], b0[n], acc[m][n], 0, 0, 0);
    __builtin_amdgcn_s_setprio(0);

    if (pf) stageA_set(tc + 1);

    // ---- C1: A-lo x kk1 ----
    __builtin_amdgcn_s_setprio(1);
#pragma unroll
    for (int m = 0; m < 4; ++m)
#pragma unroll
      for (int n = 0; n < 4; ++n)
        acc[m][n] = __builtin_amdgcn_mfma_f32_16x16x32_bf16(a1[m], b1[n], acc[m][n], 0, 0, 0);
    __builtin_amdgcn_s_setprio(0);

    // ---- mid: force A-late(tc) landed; leave B+A(tc+1) (8) in flight ----
    if (pf) asm volatile("s_waitcnt vmcnt(8)" ::: "memory");
    else    asm volatile("s_waitcnt vmcnt(0)" ::: "memory");
    __builtin_amdgcn_s_barrier();
    asm volatile("" ::: "memory");

    // ---- A-hi reads (8) then C2, C3 ----
    bf16x8 h0[4], h1[4];
#pragma unroll
    for (int m = 0; m < 4; ++m) h0[m] = *(const bf16x8*)(Ab + a_slot(4 + m) + cx0);
#pragma unroll
    for (int m = 0; m < 4; ++m) h1[m] = *(const bf16x8*)(Ab + a_slot(4 + m) + cx1);

    __builtin_amdgcn_s_setprio(1);
#pragma unroll
    for (int m = 0; m < 4; ++m)
#pragma unroll
      for (int n = 0; n < 4; ++n)
        acc[4 + m][n] = __builtin_amdgcn_mfma_f32_16x16x32_bf16(h0[m], b0[n], acc[4 + m][n], 0, 0, 0);
    __builtin_amdgcn_s_setprio(0);
    __builtin_amdgcn_s_setprio(1);
#pragma unroll
    for (int m = 0; m < 4; ++m)
#pragma unroll
      for (int n = 0; n < 4; ++n)
        acc[4 + m][n] = __builtin_amdgcn_mfma_f32_16x16x32_bf16(h1[m], b1[n], acc[4 + m][n], 0, 0, 0);
    __builtin_amdgcn_s_setprio(0);

    // ---- boundary: force B+A-early(tc+1); leave A-late(tc+1) in flight ----
    if (pf) asm volatile("s_waitcnt vmcnt(2)" ::: "memory");
    else    asm volatile("s_waitcnt vmcnt(0)" ::: "memory");
    __builtin_amdgcn_s_barrier();
    asm volatile("" ::: "memory");
  }

  // ---- epilogue ----
  if constexpr (EPI == 2) {
#pragma unroll
    for (int n = 0; n < 4; ++n) {
      const int col = col0 + wn * 64 + n * 16 + fr;
      const float bi = bias[col];
#pragma unroll
      for (int m = 0; m < 8; ++m)
#pragma unroll
        for (int e = 0; e < 4; ++e) {
          const int row = row0 + wm * 128 + m * 16 + q4 * 4 + e;
          Hres[(size_t)row * N + col] += acc[m][n][e] + bi;
        }
    }
  } else {
    char* wreg = (char*)smem + wid * 9216;   // 64 rows x 144 B per wave
    float bi[4];
#pragma unroll
    for (int n = 0; n < 4; ++n) bi[n] = bias[col0 + wn * 64 + n * 16 + fr];
#pragma unroll
    for (int half = 0; half < 2; ++half) {
#pragma unroll
      for (int m = 0; m < 4; ++m)
#pragma unroll
        for (int n = 0; n < 4; ++n)
#pragma unroll
          for (int e = 0; e < 4; ++e) {
            float v = acc[half * 4 + m][n][e] + bi[n];
            if (EPI == 1) v = gelu_new(v);
            *(unsigned short*)(wreg + (m * 16 + q4 * 4 + e) * 144 +
                               (n * 16 + fr) * 2) = f2bf(v);
          }
#pragma unroll
      for (int rb = 0; rb < 8; ++rb) {
        const int rowl = rb * 8 + (l >> 3);
        u16x8 vv = *(const u16x8*)(wreg + rowl * 144 + (l & 7) * 16);
        const int rg = row0 + wm * 128 + half * 64 + rowl;
        *(u16x8*)(Cb + (size_t)rg * N + col0 + wn * 64 + (l & 7) * 8) = vv;
      }
    }
  }
}

// ---------------------------------------------------------------------------
// MFMA flash attention (unchanged; verified rounds 3-7).
// ---------------------------------------------------------------------------
__global__ __launch_bounds__(256) void attn_mfma(
    const unsigned short* __restrict__ qkv, unsigned short* __restrict__ aout,
    int b0) {
  __shared__ alignas(16) unsigned short Klds[256 * 64];
  __shared__ alignas(16) unsigned short Vt[64 * 256];
  const int bh = blockIdx.x;
  const int bl = bh >> 4, hd = bh & 15;
  const size_t base = (size_t)bl * 256 * 3072 + (size_t)hd * 64;
  const int t = threadIdx.x;
  const int w = t >> 6, l = t & 63;
  const int lq = l & 31, hl = l >> 5;

#pragma unroll
  for (int i = 0; i < 8; ++i) {
    const int r = i * 32 + (t >> 3);
    const int c = t & 7;
    u16x8 kv = *(const u16x8*)(qkv + base + (size_t)r * 3072 + 1024 + c * 8);
    *(u16x8*)(Klds + r * 64 + ((c ^ (r & 7)) * 8)) = kv;
    u16x8 vv = *(const u16x8*)(qkv + base + (size_t)r * 3072 + 2048 + c * 8);
#pragma unroll
    for (int j = 0; j < 8; ++j) {
      const int d = c * 8 + j;
      Vt[d * 256 + (((r >> 3) ^ (d & 31)) * 8) + (r & 7)] = vv[j];
    }
  }

  const int q0 = w * 64;
  bf16x8 qf[2][4];
#pragma unroll
  for (int n = 0; n < 2; ++n)
#pragma unroll
    for (int d16 = 0; d16 < 4; ++d16)
      qf[n][d16] = *(const bf16x8*)(qkv + base +
          (size_t)(q0 + n * 32 + lq) * 3072 + d16 * 16 + hl * 8);
  __syncthreads();

  const float cs = 0.125f * 1.44269504088896f;
  f32x16 O[2][2];
#pragma unroll
  for (int m = 0; m < 2; ++m)
#pragma unroll
    for (int n = 0; n < 2; ++n)
#pragma unroll
      for (int e = 0; e < 16; ++e) O[m][n][e] = 0.f;
  float mrun[2] = {-3.0e38f, -3.0e38f};
  float lrun[2] = {0.f, 0.f};

  const int ktmax = (q0 + 63) >> 5;
  for (int kt = 0; kt <= ktmax; ++kt) {
    bf16x8 kf[4];
    const int krow = kt * 32 + lq;
#pragma unroll
    for (int d16 = 0; d16 < 4; ++d16) {
      const int chunk = (d16 * 2 + hl) ^ (krow & 7);
      kf[d16] = *(const bf16x8*)(Klds + krow * 64 + chunk * 8);
    }
    const int nlo = (kt * 32 > q0 + 31) ? 1 : 0;
    bf16x8 pfrag[2][2];
#pragma unroll
    for (int n = 0; n < 2; ++n) {
      if (n < nlo) continue;
      f32x16 s;
#pragma unroll
      for (int e = 0; e < 16; ++e) s[e] = 0.f;
#pragma unroll
      for (int d16 = 0; d16 < 4; ++d16)
        s = __builtin_amdgcn_mfma_f32_32x32x16_bf16(kf[d16], qf[n][d16], s, 0, 0, 0);
      const int qg = q0 + n * 32 + lq;
      float sv[16];
#pragma unroll
      for (int r = 0; r < 16; ++r) {
        const int kg = kt * 32 + (r & 3) + 8 * (r >> 2) + 4 * hl;
        const float x = s[r] * cs;
        sv[r] = (kg > qg) ? -3.0e38f : x;
      }
      float pmax = sv[0];
#pragma unroll
      for (int r = 1; r < 16; ++r) pmax = fmaxf(pmax, sv[r]);
      pmax = fmaxf(pmax, __shfl_xor(pmax, 32, 64));
      const float nm = fmaxf(mrun[n], pmax);
      const float alpha = exp2f(mrun[n] - nm);
      mrun[n] = nm;
      float psum = 0.f;
#pragma unroll
      for (int r = 0; r < 16; ++r) {
        sv[r] = exp2f(sv[r] - nm);
        psum += sv[r];
      }
      psum += __shfl_xor(psum, 32, 64);
      lrun[n] = lrun[n] * alpha + psum;
#pragma unroll
      for (int m = 0; m < 2; ++m)
#pragma unroll
        for (int e = 0; e < 16; ++e) O[m][n][e] *= alpha;
#pragma unroll
      for (int h = 0; h < 2; ++h) {
        unsigned int a0 = cvtpk(sv[h * 8 + 0], sv[h * 8 + 1]);
        unsigned int a1 = cvtpk(sv[h * 8 + 2], sv[h * 8 + 3]);
        unsigned int c0 = cvtpk(sv[h * 8 + 4], sv[h * 8 + 5]);
        unsigned int c1 = cvtpk(sv[h * 8 + 6], sv[h * 8 + 7]);
        plswap(a0, c0);
        plswap(a1, c1);
        u32x4 fw; fw.x = a0; fw.y = a1; fw.z = c0; fw.w = c1;
        pfrag[n][h] = __builtin_bit_cast(bf16x8, fw);
      }
    }
#pragma unroll
    for (int m = 0; m < 2; ++m)
#pragma unroll
      for (int h = 0; h < 2; ++h) {
        const int dd = m * 32 + lq;
        const int chunk = (kt * 4 + h * 2 + hl) ^ (dd & 31);
        bf16x8 vf = *(const bf16x8*)(Vt + dd * 256 + chunk * 8);
#pragma unroll
        for (int n = 0; n < 2; ++n)
          if (n >= nlo)
            O[m][n] = __builtin_amdgcn_mfma_f32_32x32x16_bf16(vf, pfrag[n][h], O[m][n], 0, 0, 0);
      }
  }

#pragma unroll
  for (int n = 0; n < 2; ++n) {
    const float inv = 1.0f / lrun[n];
    const size_t row = (size_t)(b0 + bl) * 256 + q0 + n * 32 + lq;
#pragma unroll
    for (int m = 0; m < 2; ++m) {
#pragma unroll
      for (int qd = 0; qd < 4; ++qd) {
        u16x4 pk;
#pragma unroll
        for (int e = 0; e < 4; ++e) pk[e] = f2bf(O[m][n][qd * 4 + e] * inv);
        *(u16x4*)(aout + row * 1024 + hd * 64 + m * 32 + qd * 8 + hl * 4) = pk;
      }
    }
  }
}

// ---------------------------------------------------------------------------
// Loss
// ---------------------------------------------------------------------------
__device__ __forceinline__ float block_reduce_sum256(float v) {
#pragma unroll
  for (int off = 32; off; off >>= 1) v += __shfl_xor(v, off, 64);
  __shared__ float red[4];
  const int t = threadIdx.x;
  if ((t & 63) == 0) red[t >> 6] = v;
  __syncthreads();
  return red[0] + red[1] + red[2] + red[3];
}

__global__ __launch_bounds__(256) void loss_partial(
    const float* __restrict__ hf, const float* __restrict__ sent,
    float* __restrict__ part) {
  const int s = blockIdx.x, t = threadIdx.x;
  f32x4 a = ((const f32x4*)(hf + (size_t)s * 1024))[t];
  f32x4 b = ((const f32x4*)(sent + (size_t)(s + 1) * 1024))[t];
  f32x4 d = a - b;
  float v = d.x * d.x + d.y * d.y + d.z * d.z + d.w * d.w;
  float tot = block_reduce_sum256(v);
  if (t == 0) part[s] = tot;
}

__global__ __launch_bounds__(256) void loss_final(
    const float* __restrict__ part, float* __restrict__ out) {
  const int t = threadIdx.x;
  float v = (t < 255) ? part[t] : 0.f;
  float s = block_reduce_sum256(v);
  if (t == 0) out[0] = s * (1.0f / (255.0f * 1024.0f));
}

// ---------------------------------------------------------------------------
// Workspace layouts
// Chunked (fallback, ~120 MiB) and Full-M (~184 MiB, used if ws_size allows)
// ---------------------------------------------------------------------------
constexpr size_t C_X     = 0;
constexpr size_t C_QKV   = 33554432;
constexpr size_t C_WQKV  = C_QKV + 67108864;
constexpr size_t C_WPROJ = C_WQKV + 6291456;
constexpr size_t C_WFC   = C_WPROJ + 2097152;
constexpr size_t C_WMLP  = C_WFC + 8388608;
constexpr size_t C_PART  = C_WMLP + 8388608;

constexpr size_t F_X     = 0;                      // 32 MiB
constexpr size_t F_U     = 33554432;               // union qkv 96 / m 128 MiB
constexpr size_t F_WQKV  = F_U + 134217728;
constexpr size_t F_WPROJ = F_WQKV + 6291456;
constexpr size_t F_WFC   = F_WPROJ + 2097152;
constexpr size_t F_WMLP  = F_WFC + 8388608;
constexpr size_t F_PART  = F_WMLP + 8388608;
constexpr size_t F_NEED  = F_PART + 4096;

extern "C" void kernel_launch(void* const* d_in, const int* in_sizes, int n_in,
                              void* d_out, int out_size, void* d_ws, size_t ws_size,
                              hipStream_t stream) {
  (void)in_sizes; (void)n_in; (void)out_size;
  const float* sent    = (const float*)d_in[0];
  const float* wpe     = (const float*)d_in[1];
  const float* ln1_g   = (const float*)d_in[2];
  const float* ln1_b   = (const float*)d_in[3];
  const float* attn_w  = (const float*)d_in[4];
  const float* attn_b  = (const float*)d_in[5];
  const float* attn_pw = (const float*)d_in[6];
  const float* attn_pb = (const float*)d_in[7];
  const float* ln2_g   = (const float*)d_in[8];
  const float* ln2_b   = (const float*)d_in[9];
  const float* fc_w    = (const float*)d_in[10];
  const float* fc_b    = (const float*)d_in[11];
  const float* mlp_w   = (const float*)d_in[12];
  const float* mlp_b   = (const float*)d_in[13];
  const float* lnf_g   = (const float*)d_in[14];
  const float* lnf_b   = (const float*)d_in[15];
  float* out_h = (float*)d_out;
  float* h = out_h;

  char* ws = (char*)d_ws;
  const bool fullm = ws_size >= F_NEED;

  unsigned short* xb    = (unsigned short*)(ws + (fullm ? F_X : C_X));
  unsigned short* ub    = (unsigned short*)(ws + (fullm ? F_U : C_QKV));
  unsigned short* wqkv  = (unsigned short*)(ws + (fullm ? F_WQKV : C_WQKV));
  unsigned short* wproj = (unsigned short*)(ws + (fullm ? F_WPROJ : C_WPROJ));
  unsigned short* wfc   = (unsigned short*)(ws + (fullm ? F_WFC : C_WFC));
  unsigned short* wmlp  = (unsigned short*)(ws + (fullm ? F_WMLP : C_WMLP));
  float* part           = (float*)(ws + (fullm ? F_PART : C_PART));

  const dim3 tb(32, 8, 1);
  for (int i = 0; i < 2; ++i) {
    transpose_bf16<<<dim3(96, 32), tb, 0, stream>>>(
        attn_w + (size_t)i * 1024 * 3072, wqkv, 1024, 3072);
    transpose_bf16<<<dim3(32, 32), tb, 0, stream>>>(
        attn_pw + (size_t)i * 1024 * 1024, wproj, 1024, 1024);
    transpose_bf16<<<dim3(128, 32), tb, 0, stream>>>(
        fc_w + (size_t)i * 1024 * 4096, wfc, 1024, 4096);
    transpose_bf16<<<dim3(32, 128), tb, 0, stream>>>(
        mlp_w + (size_t)i * 4096 * 1024, wmlp, 4096, 1024);

    // --- attention block ---
    if (i == 0)
      ln_wpe_kernel<<<16384, 256, 0, stream>>>(sent, wpe, ln1_g, ln1_b, h, xb);
    else
      ln_kernel<0><<<16384, 256, 0, stream>>>(h, ln1_g + i * 1024, ln1_b + i * 1024, xb);

    if (fullm) {
      gemmp<0><<<768, 512, 0, stream>>>(
          xb, wqkv, attn_b + i * 3072, ub, nullptr, 3072, 1024, 12, 64);
      attn_mfma<<<1024, 256, 0, stream>>>(ub, xb, 0);
    } else {
      for (int c = 0; c < 2; ++c) {
        const size_t r0 = (size_t)c * 8192;
        gemmp<0><<<384, 512, 0, stream>>>(
            xb + r0 * 1024, wqkv, attn_b + i * 3072, ub, nullptr, 3072, 1024, 12, 32);
        attn_mfma<<<512, 256, 0, stream>>>(ub, xb, c * 32);
      }
    }
    gemmp<2><<<256, 512, 0, stream>>>(
        xb, wproj, attn_pb + i * 1024, nullptr, h, 1024, 1024, 4, 64);

    // --- MLP block ---
    ln_kernel<0><<<16384, 256, 0, stream>>>(h, ln2_g + i * 1024, ln2_b + i * 1024, xb);
    if (fullm) {
      gemmp<1><<<1024, 512, 0, stream>>>(
          xb, wfc, fc_b + i * 4096, ub, nullptr, 4096, 1024, 16, 64);
      gemmp<2><<<256, 512, 0, stream>>>(
          ub, wmlp, mlp_b + i * 1024, nullptr, h, 1024, 4096, 4, 64);
    } else {
      for (int c = 0; c < 2; ++c) {
        const size_t r0 = (size_t)c * 8192;
        gemmp<1><<<512, 512, 0, stream>>>(
            xb + r0 * 1024, wfc, fc_b + i * 4096, ub, nullptr, 4096, 1024, 16, 32);
        gemmp<2><<<128, 512, 0, stream>>>(
            ub, wmlp, mlp_b + i * 1024, nullptr, h + r0 * 1024, 1024, 4096, 4, 32);
      }
    }
  }

  ln_kernel<1><<<16384, 256, 0, stream>>>(h, lnf_g, lnf_b, out_h);
  loss_partial<<<255, 256, 0, stream>>>(out_h, sent, part);
  loss_final<<<1, 256, 0, stream>>>(part, out_h + 16777216);
}